// Round 1
// baseline (546.734 us; speedup 1.0000x reference)
//
#include <hip/hip_runtime.h>
#include <math.h>

#define NN 2048
#define NEG 0.2f

__device__ __forceinline__ float dot4(float4 a, float4 b) {
  return a.x * b.x + a.y * b.y + a.z * b.z + a.w * b.w;
}

// ---------------------------------------------------------------------------
// K1: x = bio @ initW^T + initb      rows = [g][b][n] (16384), K=256, out 128
// ---------------------------------------------------------------------------
__global__ __launch_bounds__(256) void k1_init(const float* __restrict__ bioA,
                                               const float* __restrict__ bioB,
                                               const float* __restrict__ W,
                                               const float* __restrict__ bias,
                                               float* __restrict__ xout) {
  __shared__ float As[32][36];
  __shared__ float Ws[32][132];
  const int t = threadIdx.x;
  const int m0 = blockIdx.x * 32;
  const float* A = (m0 < 8192) ? bioA : bioB;
  const int arow0 = (m0 < 8192) ? m0 : (m0 - 8192);
  const int og = t & 31, ig = t >> 5;
  float acc[4][4] = {};
  for (int kt = 0; kt < 256; kt += 32) {
    __syncthreads();
    {
      const int r = t >> 3, kq = t & 7;
      const float4 v = *(const float4*)&A[(arow0 + r) * 256 + kt + kq * 4];
      As[kq * 4 + 0][r] = v.x; As[kq * 4 + 1][r] = v.y;
      As[kq * 4 + 2][r] = v.z; As[kq * 4 + 3][r] = v.w;
    }
#pragma unroll
    for (int u = 0; u < 4; ++u) {
      const int f = u * 256 + t;
      const int o = f >> 3, kq = f & 7;
      const float4 v = *(const float4*)&W[o * 256 + kt + kq * 4];
      Ws[kq * 4 + 0][o] = v.x; Ws[kq * 4 + 1][o] = v.y;
      Ws[kq * 4 + 2][o] = v.z; Ws[kq * 4 + 3][o] = v.w;
    }
    __syncthreads();
#pragma unroll
    for (int kk = 0; kk < 32; ++kk) {
      const float4 a4 = *(const float4*)&As[kk][ig * 4];
      const float4 w4 = *(const float4*)&Ws[kk][og * 4];
      const float av[4] = {a4.x, a4.y, a4.z, a4.w};
      const float wv[4] = {w4.x, w4.y, w4.z, w4.w};
#pragma unroll
      for (int ii = 0; ii < 4; ++ii)
#pragma unroll
        for (int jj = 0; jj < 4; ++jj) acc[ii][jj] += av[ii] * wv[jj];
    }
  }
  const float4 b4 = *(const float4*)&bias[og * 4];
#pragma unroll
  for (int ii = 0; ii < 4; ++ii) {
    const int row = m0 + ig * 4 + ii;
    float4 o4;
    o4.x = acc[ii][0] + b4.x; o4.y = acc[ii][1] + b4.y;
    o4.z = acc[ii][2] + b4.z; o4.w = acc[ii][3] + b4.w;
    *(float4*)&xout[row * 128 + og * 4] = o4;
  }
}

// ---------------------------------------------------------------------------
// K2: y = x @ projW^T (no bias); write xh[g][b][h][n][k]; s1,s2[g][b][h][n]
// ---------------------------------------------------------------------------
__global__ __launch_bounds__(256) void k2_proj(const float* __restrict__ x,
                                               const float* __restrict__ W,
                                               const float* __restrict__ attw,
                                               float* __restrict__ xh,
                                               float* __restrict__ s1,
                                               float* __restrict__ s2) {
  __shared__ float As[32][36];
  __shared__ float Ws[32][132];
  const int t = threadIdx.x;
  const int m0 = blockIdx.x * 32;
  const int og = t & 31, ig = t >> 5;
  float acc[4][4] = {};
  for (int kt = 0; kt < 128; kt += 32) {
    __syncthreads();
    {
      const int r = t >> 3, kq = t & 7;
      const float4 v = *(const float4*)&x[(m0 + r) * 128 + kt + kq * 4];
      As[kq * 4 + 0][r] = v.x; As[kq * 4 + 1][r] = v.y;
      As[kq * 4 + 2][r] = v.z; As[kq * 4 + 3][r] = v.w;
    }
#pragma unroll
    for (int u = 0; u < 4; ++u) {
      const int f = u * 256 + t;
      const int o = f >> 3, kq = f & 7;
      const float4 v = *(const float4*)&W[o * 128 + kt + kq * 4];
      Ws[kq * 4 + 0][o] = v.x; Ws[kq * 4 + 1][o] = v.y;
      Ws[kq * 4 + 2][o] = v.z; Ws[kq * 4 + 3][o] = v.w;
    }
    __syncthreads();
#pragma unroll
    for (int kk = 0; kk < 32; ++kk) {
      const float4 a4 = *(const float4*)&As[kk][ig * 4];
      const float4 w4 = *(const float4*)&Ws[kk][og * 4];
      const float av[4] = {a4.x, a4.y, a4.z, a4.w};
      const float wv[4] = {w4.x, w4.y, w4.z, w4.w};
#pragma unroll
      for (int ii = 0; ii < 4; ++ii)
#pragma unroll
        for (int jj = 0; jj < 4; ++jj) acc[ii][jj] += av[ii] * wv[jj];
    }
  }
  // epilogue: o = og*4+oo ; h = o/32, k = o%32
  const int h = og >> 3;
  const int k4 = (og & 7) * 4;
  const int g = m0 >> 13;
  const int bb = (m0 >> 11) & 3;
  const int gb = g * 4 + bb;
  const int n0 = (m0 & 2047) + ig * 4;
  const float4 w1 = *(const float4*)&attw[h * 64 + k4];
  const float4 w2 = *(const float4*)&attw[h * 64 + 32 + k4];
  float p1[4], p2[4];
#pragma unroll
  for (int ii = 0; ii < 4; ++ii) {
    float4 v;
    v.x = acc[ii][0]; v.y = acc[ii][1]; v.z = acc[ii][2]; v.w = acc[ii][3];
    *(float4*)&xh[((gb * 4 + h) * NN + (n0 + ii)) * 32 + k4] = v;
    p1[ii] = dot4(v, w1);
    p2[ii] = dot4(v, w2);
  }
#pragma unroll
  for (int s = 1; s < 8; s <<= 1) {
#pragma unroll
    for (int ii = 0; ii < 4; ++ii) {
      p1[ii] += __shfl_xor(p1[ii], s);
      p2[ii] += __shfl_xor(p2[ii], s);
    }
  }
  if ((og & 7) == 0) {
#pragma unroll
    for (int ii = 0; ii < 4; ++ii) {
      s1[(gb * 4 + h) * NN + n0 + ii] = p1[ii];
      s2[(gb * 4 + h) * NN + n0 + ii] = p2[ii];
    }
  }
}

// ---------------------------------------------------------------------------
// K3: masked GAT attention + PV + relu + residual -> G[g][b][n][128]
// block = (g,b, 32-row tile), 256 threads (wave = head)
// ---------------------------------------------------------------------------
__global__ __launch_bounds__(256) void k3_attn(const float* __restrict__ xh,
                                               const float* __restrict__ s1w,
                                               const float* __restrict__ s2w,
                                               const int* __restrict__ adjA,
                                               const int* __restrict__ adjB,
                                               const float* __restrict__ attb,
                                               const float* __restrict__ x,
                                               float* __restrict__ G) {
  __shared__ float pT[4][64][36];  // [h][j][i] stride 36: b128-readable, few conflicts
  __shared__ float sc1[32][4];
  __shared__ float denA[32][4];
  __shared__ float denB[32][4];
  const int t = threadIdx.x;
  const int wave = t >> 6, lane = t & 63;
  const int blk = blockIdx.x;
  const int g = blk >> 8;
  const int b = (blk >> 6) & 3;
  const int i0 = (blk & 63) * 32;
  const int gb = g * 4 + b;
  const int* adj = (g ? adjB : adjA) + b * NN * NN;
  if (t < 128) {
    const int i = t & 31, h = t >> 5;
    sc1[i][h] = s1w[(gb * 4 + h) * NN + i0 + i] + attb[h];
    denA[i][h] = 0.f;
    denB[i][h] = 0.f;
  }
  const int h_acc = wave;
  const int ig = lane >> 3;
  const int k4 = (lane & 7) * 4;
  const float* xhh = xh + ((gb * 4 + h_acc) * NN) * 32;
  float acc[4][4] = {};
  for (int jt = 0; jt < 32; ++jt) {
    __syncthreads();  // previous tile fully consumed
    const int jg = jt * 64 + lane;
    float s2v[4];
#pragma unroll
    for (int h = 0; h < 4; ++h) s2v[h] = s2w[(gb * 4 + h) * NN + jg];
#pragma unroll
    for (int v = 0; v < 8; ++v) {
      const int i_loc = wave + v * 4;
      const int av = adj[(i0 + i_loc) * NN + jg];
#pragma unroll
      for (int h = 0; h < 4; ++h) {
        float s = sc1[i_loc][h] + s2v[h];
        s = (s >= 0.f) ? s : NEG * s;
        pT[h][lane][i_loc] = (av > 0) ? __expf(s) : 0.f;
      }
    }
    __syncthreads();
    {  // denom partials (read-only on pT, no sync needed vs acc phase)
      const int i = t & 31, hh = (t >> 5) & 3;
      const int jb = (t >> 7) * 32;
      float sum = 0.f;
#pragma unroll
      for (int jj = 0; jj < 32; ++jj) sum += pT[hh][jb + jj][i];
      if (t < 128) denA[i][hh] += sum; else denB[i][hh] += sum;
    }
    const float* xhj = xhh + (jt * 64) * 32 + k4;
#pragma unroll 4
    for (int j2 = 0; j2 < 64; ++j2) {
      const float4 p4 = *(const float4*)&pT[h_acc][j2][ig * 4];
      const float4 x4 = *(const float4*)&xhj[j2 * 32];
      const float pv[4] = {p4.x, p4.y, p4.z, p4.w};
      const float xv[4] = {x4.x, x4.y, x4.z, x4.w};
#pragma unroll
      for (int ii = 0; ii < 4; ++ii)
#pragma unroll
        for (int kk = 0; kk < 4; ++kk) acc[ii][kk] += pv[ii] * xv[kk];
    }
  }
  __syncthreads();
#pragma unroll
  for (int ii = 0; ii < 4; ++ii) {
    const int i = ig * 4 + ii;
    const int row = i0 + i;
    const float den = denA[i][h_acc] + denB[i][h_acc];
    const float inv = 1.f / den;
    const int off = (gb * NN + row) * 128 + h_acc * 32 + k4;
    const float4 xr = *(const float4*)&x[off];
    float4 o4;
    o4.x = fmaxf(acc[ii][0] * inv, 0.f) + xr.x;
    o4.y = fmaxf(acc[ii][1] * inv, 0.f) + xr.y;
    o4.z = fmaxf(acc[ii][2] * inv, 0.f) + xr.z;
    o4.w = fmaxf(acc[ii][3] * inv, 0.f) + xr.w;
    *(float4*)&G[off] = o4;
  }
}

// ---------------------------------------------------------------------------
// K4: per (g,b): h = GGE(in); e[gb][0:128]=h; e[gb][128:256]=GAGA(G, h)
// ---------------------------------------------------------------------------
__global__ __launch_bounds__(256) void k4_gaga(const float* __restrict__ a_in,
                                               const float* __restrict__ b_in,
                                               const float* __restrict__ ggeW1,
                                               const float* __restrict__ ggeb1,
                                               const float* __restrict__ ggeW2,
                                               const float* __restrict__ ggeb2,
                                               const float* __restrict__ G,
                                               float* __restrict__ e) {
  __shared__ float inL[512];
  __shared__ float h1L[128];
  __shared__ float hvL[128];
  __shared__ float lg[2048];
  __shared__ float red[8][128];
  __shared__ float tred[256];
  const int t = threadIdx.x;
  const int wave = t >> 6, lane = t & 63;
  const int g = blockIdx.x >> 2, b = blockIdx.x & 3;
  const int gb2 = g * 4 + b;
  const float* inp = (g ? b_in : a_in) + b * 512;
  if (t < 128) *(float4*)&inL[t * 4] = *(const float4*)&inp[t * 4];
  __syncthreads();
  // h1 = relu(in @ W1^T + b1), wave-per-2-outputs
  for (int p = 0; p < 16; ++p) {
    const int o0 = p * 8 + wave * 2;
    const float* w0 = &ggeW1[o0 * 512 + lane * 8];
    const float* w1 = &ggeW1[(o0 + 1) * 512 + lane * 8];
    const float4 i0v = *(const float4*)&inL[lane * 8];
    const float4 i1v = *(const float4*)&inL[lane * 8 + 4];
    float s0 = dot4(*(const float4*)&w0[0], i0v) + dot4(*(const float4*)&w0[4], i1v);
    float s1v = dot4(*(const float4*)&w1[0], i0v) + dot4(*(const float4*)&w1[4], i1v);
#pragma unroll
    for (int s = 1; s < 64; s <<= 1) { s0 += __shfl_xor(s0, s); s1v += __shfl_xor(s1v, s); }
    if (lane == 0) {
      h1L[o0] = fmaxf(s0 + ggeb1[o0], 0.f);
      h1L[o0 + 1] = fmaxf(s1v + ggeb1[o0 + 1], 0.f);
    }
  }
  __syncthreads();
  // hv = relu(h1 @ W2^T + b2)
  for (int p = 0; p < 16; ++p) {
    const int o0 = p * 8 + wave * 2;
    const float2 w0 = *(const float2*)&ggeW2[o0 * 128 + lane * 2];
    const float2 w1 = *(const float2*)&ggeW2[(o0 + 1) * 128 + lane * 2];
    const float2 hv = *(const float2*)&h1L[lane * 2];
    float s0 = w0.x * hv.x + w0.y * hv.y;
    float s1v = w1.x * hv.x + w1.y * hv.y;
#pragma unroll
    for (int s = 1; s < 64; s <<= 1) { s0 += __shfl_xor(s0, s); s1v += __shfl_xor(s1v, s); }
    if (lane == 0) {
      hvL[o0] = fmaxf(s0 + ggeb2[o0], 0.f);
      hvL[o0 + 1] = fmaxf(s1v + ggeb2[o0 + 1], 0.f);
    }
  }
  __syncthreads();
  if (t < 128) e[gb2 * 256 + t] = hvL[t];
  // GAGA logits: lg[n] = G[n,:] . hv   (32 d-lanes x 8 n-groups)
  const float* Gb = G + gb2 * NN * 128;
  const int dg = t & 31, ng8 = t >> 5;
  const float4 hv4 = *(const float4*)&hvL[dg * 4];
  for (int nb = 0; nb < 256; ++nb) {
    const int n = nb * 8 + ng8;
    const float4 gv = *(const float4*)&Gb[n * 128 + dg * 4];
    float part = dot4(gv, hv4);
#pragma unroll
    for (int s = 1; s < 32; s <<= 1) part += __shfl_xor(part, s);
    if (dg == 0) lg[n] = part;
  }
  __syncthreads();
  // softmax over n (needs max: logits can be ~±30)
  float m = -1e30f;
  for (int n = t; n < 2048; n += 256) m = fmaxf(m, lg[n]);
  tred[t] = m;
  __syncthreads();
#pragma unroll
  for (int s = 128; s > 0; s >>= 1) {
    if (t < s) tred[t] = fmaxf(tred[t], tred[t + s]);
    __syncthreads();
  }
  const float mx = tred[0];
  __syncthreads();
  float z = 0.f;
  for (int n = t; n < 2048; n += 256) {
    const float pv = __expf(lg[n] - mx);
    lg[n] = pv;
    z += pv;
  }
  tred[t] = z;
  __syncthreads();
#pragma unroll
  for (int s = 128; s > 0; s >>= 1) {
    if (t < s) tred[t] += tred[t + s];
    __syncthreads();
  }
  const float Z = tred[0];
  // e2[d] = sum_n p_n * G[n][d] / Z
  float4 acc4 = {0.f, 0.f, 0.f, 0.f};
  for (int n = ng8; n < 2048; n += 8) {
    const float pv = lg[n];
    const float4 gv = *(const float4*)&Gb[n * 128 + dg * 4];
    acc4.x += pv * gv.x; acc4.y += pv * gv.y;
    acc4.z += pv * gv.z; acc4.w += pv * gv.w;
  }
  *(float4*)&red[ng8][dg * 4] = acc4;
  __syncthreads();
  if (t < 128) {
    float ssum = 0.f;
#pragma unroll
    for (int q = 0; q < 8; ++q) ssum += red[q][t];
    e[gb2 * 256 + 128 + t] = ssum / Z;
  }
}

// ---------------------------------------------------------------------------
// K5: LED head per batch: cnn/maxpool, concat, 2-layer MLP, log_softmax
// ---------------------------------------------------------------------------
__global__ __launch_bounds__(256) void k5_led(const float* __restrict__ e,
                                              const float* __restrict__ convW,
                                              const float* __restrict__ convb,
                                              const float* __restrict__ ledW1,
                                              const float* __restrict__ ledb1,
                                              const float* __restrict__ ledW2,
                                              const float* __restrict__ ledb2,
                                              float* __restrict__ out) {
  __shared__ float eaL[256], ebL[256], uL[512], xL[128], lgL[2];
  const int t = threadIdx.x;
  const int wave = t >> 6, lane = t & 63;
  const int bt = blockIdx.x;
  if (t < 64) {
    *(float4*)&eaL[t * 4] = *(const float4*)&e[bt * 256 + t * 4];
    *(float4*)&ebL[t * 4] = *(const float4*)&e[(4 + bt) * 256 + t * 4];
  }
  __syncthreads();
  uL[256 + t] = eaL[t] - ebL[t];
  const float4 ea4 = *(const float4*)&eaL[lane * 4];
  const float4 eb4 = *(const float4*)&ebL[lane * 4];
  for (int p = 0; p < 32; ++p) {
    const int o0 = p * 8 + wave * 2;
    const float4 w0 = *(const float4*)&convW[o0 * 256 + lane * 4];
    const float4 w1 = *(const float4*)&convW[(o0 + 1) * 256 + lane * 4];
    float sa0 = dot4(w0, ea4), sb0 = dot4(w0, eb4);
    float sa1 = dot4(w1, ea4), sb1 = dot4(w1, eb4);
#pragma unroll
    for (int s = 1; s < 64; s <<= 1) {
      sa0 += __shfl_xor(sa0, s); sb0 += __shfl_xor(sb0, s);
      sa1 += __shfl_xor(sa1, s); sb1 += __shfl_xor(sb1, s);
    }
    if (lane == 0) {
      const float c0 = convb[o0], c1 = convb[o0 + 1];
      uL[o0] = fmaxf(sa0 + c0, sb0 + c0);
      uL[o0 + 1] = fmaxf(sa1 + c1, sb1 + c1);
    }
  }
  __syncthreads();
  for (int p = 0; p < 16; ++p) {
    const int o0 = p * 8 + wave * 2;
    const float* w0 = &ledW1[o0 * 512 + lane * 8];
    const float* w1 = &ledW1[(o0 + 1) * 512 + lane * 8];
    const float4 u0 = *(const float4*)&uL[lane * 8];
    const float4 u1 = *(const float4*)&uL[lane * 8 + 4];
    float s0 = dot4(*(const float4*)&w0[0], u0) + dot4(*(const float4*)&w0[4], u1);
    float s1v = dot4(*(const float4*)&w1[0], u0) + dot4(*(const float4*)&w1[4], u1);
#pragma unroll
    for (int s = 1; s < 64; s <<= 1) { s0 += __shfl_xor(s0, s); s1v += __shfl_xor(s1v, s); }
    if (lane == 0) {
      xL[o0] = fmaxf(s0 + ledb1[o0], 0.f);
      xL[o0 + 1] = fmaxf(s1v + ledb1[o0 + 1], 0.f);
    }
  }
  __syncthreads();
  if (wave < 2) {
    const float2 w = *(const float2*)&ledW2[wave * 128 + lane * 2];
    const float2 xv = *(const float2*)&xL[lane * 2];
    float s0 = w.x * xv.x + w.y * xv.y;
#pragma unroll
    for (int s = 1; s < 64; s <<= 1) s0 += __shfl_xor(s0, s);
    if (lane == 0) lgL[wave] = s0 + ledb2[wave];
  }
  __syncthreads();
  if (t == 0) {
    const float l0 = lgL[0], l1 = lgL[1];
    const float m = fmaxf(l0, l1);
    const float za = __expf(l0 - m) + __expf(l1 - m);
    const float lz = __logf(za);
    out[bt * 2 + 0] = l0 - m - lz;
    out[bt * 2 + 1] = l1 - m - lz;
  }
}

// ---------------------------------------------------------------------------
extern "C" void kernel_launch(void* const* d_in, const int* in_sizes, int n_in,
                              void* d_out, int out_size, void* d_ws, size_t ws_size,
                              hipStream_t stream) {
  (void)in_sizes; (void)n_in; (void)out_size; (void)ws_size;
  const float* a     = (const float*)d_in[0];
  const float* bioA  = (const float*)d_in[1];
  const int*   A     = (const int*)d_in[2];
  const float* b     = (const float*)d_in[3];
  const float* bioB  = (const float*)d_in[4];
  const int*   B     = (const int*)d_in[5];
  const float* initW = (const float*)d_in[6];
  const float* initb = (const float*)d_in[7];
  const float* projW = (const float*)d_in[8];
  const float* attw  = (const float*)d_in[9];
  const float* attb  = (const float*)d_in[10];
  const float* ggeW1 = (const float*)d_in[11];
  const float* ggeb1 = (const float*)d_in[12];
  const float* ggeW2 = (const float*)d_in[13];
  const float* ggeb2 = (const float*)d_in[14];
  const float* convW = (const float*)d_in[15];
  const float* convb = (const float*)d_in[16];
  const float* ledW1 = (const float*)d_in[17];
  const float* ledb1 = (const float*)d_in[18];
  const float* ledW2 = (const float*)d_in[19];
  const float* ledb2 = (const float*)d_in[20];

  float* ws  = (float*)d_ws;
  float* x   = ws;                 // [2][4][2048][128]  2097152
  float* xh  = ws + 2097152;       // [2][4][4][2048][32] 2097152
  float* s1  = ws + 4194304;       // [2][4][4][2048]    65536
  float* s2  = ws + 4259840;       // 65536
  float* G   = ws + 4325376;       // [2][4][2048][128]  2097152
  float* e   = ws + 6422528;       // [2][4][256]        2048
  float* out = (float*)d_out;

  k1_init<<<512, 256, 0, stream>>>(bioA, bioB, initW, initb, x);
  k2_proj<<<512, 256, 0, stream>>>(x, projW, attw, xh, s1, s2);
  k3_attn<<<512, 256, 0, stream>>>(xh, s1, s2, A, B, attb, x, G);
  k4_gaga<<<8, 256, 0, stream>>>(a, b, ggeW1, ggeb1, ggeW2, ggeb2, G, e);
  k5_led<<<4, 256, 0, stream>>>(e, convW, convb, ledW1, ledb1, ledW2, ledb2, out);
}

// Round 2
// 235.502 us; speedup vs baseline: 2.3216x; 2.3216x over previous
//
#include <hip/hip_runtime.h>
#include <hip/hip_bf16.h>
#include <math.h>

#define NN 2048
#define NEG 0.2f
#define LOG2E 1.44269504f

typedef short bf16x8 __attribute__((ext_vector_type(8)));
typedef float f32x16 __attribute__((ext_vector_type(16)));

__device__ __forceinline__ float dot4(float4 a, float4 b) {
  return a.x * b.x + a.y * b.y + a.z * b.z + a.w * b.w;
}

__device__ __forceinline__ unsigned short bfbits(float f) {
  union { __hip_bfloat16 b; unsigned short u; } c;
  c.b = __float2bfloat16(f);
  return c.u;
}

// ---------------------------------------------------------------------------
// K1: x = bio @ initW^T + initb      rows = [g][b][n] (16384), K=256, out 128
// ---------------------------------------------------------------------------
__global__ __launch_bounds__(256) void k1_init(const float* __restrict__ bioA,
                                               const float* __restrict__ bioB,
                                               const float* __restrict__ W,
                                               const float* __restrict__ bias,
                                               float* __restrict__ xout) {
  __shared__ float As[32][36];
  __shared__ float Ws[32][132];
  const int t = threadIdx.x;
  const int m0 = blockIdx.x * 32;
  const float* A = (m0 < 8192) ? bioA : bioB;
  const int arow0 = (m0 < 8192) ? m0 : (m0 - 8192);
  const int og = t & 31, ig = t >> 5;
  float acc[4][4] = {};
  for (int kt = 0; kt < 256; kt += 32) {
    __syncthreads();
    {
      const int r = t >> 3, kq = t & 7;
      const float4 v = *(const float4*)&A[(arow0 + r) * 256 + kt + kq * 4];
      As[kq * 4 + 0][r] = v.x; As[kq * 4 + 1][r] = v.y;
      As[kq * 4 + 2][r] = v.z; As[kq * 4 + 3][r] = v.w;
    }
#pragma unroll
    for (int u = 0; u < 4; ++u) {
      const int f = u * 256 + t;
      const int o = f >> 3, kq = f & 7;
      const float4 v = *(const float4*)&W[o * 256 + kt + kq * 4];
      Ws[kq * 4 + 0][o] = v.x; Ws[kq * 4 + 1][o] = v.y;
      Ws[kq * 4 + 2][o] = v.z; Ws[kq * 4 + 3][o] = v.w;
    }
    __syncthreads();
#pragma unroll
    for (int kk = 0; kk < 32; ++kk) {
      const float4 a4 = *(const float4*)&As[kk][ig * 4];
      const float4 w4 = *(const float4*)&Ws[kk][og * 4];
      const float av[4] = {a4.x, a4.y, a4.z, a4.w};
      const float wv[4] = {w4.x, w4.y, w4.z, w4.w};
#pragma unroll
      for (int ii = 0; ii < 4; ++ii)
#pragma unroll
        for (int jj = 0; jj < 4; ++jj) acc[ii][jj] += av[ii] * wv[jj];
    }
  }
  const float4 b4 = *(const float4*)&bias[og * 4];
#pragma unroll
  for (int ii = 0; ii < 4; ++ii) {
    const int row = m0 + ig * 4 + ii;
    float4 o4;
    o4.x = acc[ii][0] + b4.x; o4.y = acc[ii][1] + b4.y;
    o4.z = acc[ii][2] + b4.z; o4.w = acc[ii][3] + b4.w;
    *(float4*)&xout[row * 128 + og * 4] = o4;
  }
}

// ---------------------------------------------------------------------------
// K2: y = x @ projW^T ; write xhT bf16 [gb][h][k=32][n=2048] ; s1,s2 f32
// ---------------------------------------------------------------------------
__global__ __launch_bounds__(256) void k2_proj(const float* __restrict__ x,
                                               const float* __restrict__ W,
                                               const float* __restrict__ attw,
                                               unsigned short* __restrict__ xhT,
                                               float* __restrict__ s1,
                                               float* __restrict__ s2) {
  __shared__ float As[32][36];
  __shared__ float Ws[32][132];
  const int t = threadIdx.x;
  const int m0 = blockIdx.x * 32;
  const int og = t & 31, ig = t >> 5;
  float acc[4][4] = {};
  for (int kt = 0; kt < 128; kt += 32) {
    __syncthreads();
    {
      const int r = t >> 3, kq = t & 7;
      const float4 v = *(const float4*)&x[(m0 + r) * 128 + kt + kq * 4];
      As[kq * 4 + 0][r] = v.x; As[kq * 4 + 1][r] = v.y;
      As[kq * 4 + 2][r] = v.z; As[kq * 4 + 3][r] = v.w;
    }
#pragma unroll
    for (int u = 0; u < 4; ++u) {
      const int f = u * 256 + t;
      const int o = f >> 3, kq = f & 7;
      const float4 v = *(const float4*)&W[o * 128 + kt + kq * 4];
      Ws[kq * 4 + 0][o] = v.x; Ws[kq * 4 + 1][o] = v.y;
      Ws[kq * 4 + 2][o] = v.z; Ws[kq * 4 + 3][o] = v.w;
    }
    __syncthreads();
#pragma unroll
    for (int kk = 0; kk < 32; ++kk) {
      const float4 a4 = *(const float4*)&As[kk][ig * 4];
      const float4 w4 = *(const float4*)&Ws[kk][og * 4];
      const float av[4] = {a4.x, a4.y, a4.z, a4.w};
      const float wv[4] = {w4.x, w4.y, w4.z, w4.w};
#pragma unroll
      for (int ii = 0; ii < 4; ++ii)
#pragma unroll
        for (int jj = 0; jj < 4; ++jj) acc[ii][jj] += av[ii] * wv[jj];
    }
  }
  const int h = og >> 3;
  const int k4i = (og & 7) * 4;
  const int g = m0 >> 13;
  const int bb = (m0 >> 11) & 3;
  const int gb = g * 4 + bb;
  const int n0 = (m0 & 2047) + ig * 4;
  const float4 w1 = *(const float4*)&attw[h * 64 + k4i];
  const float4 w2 = *(const float4*)&attw[h * 64 + 32 + k4i];
  float p1[4], p2[4];
#pragma unroll
  for (int ii = 0; ii < 4; ++ii) {
    float4 v;
    v.x = acc[ii][0]; v.y = acc[ii][1]; v.z = acc[ii][2]; v.w = acc[ii][3];
    p1[ii] = dot4(v, w1);
    p2[ii] = dot4(v, w2);
  }
  // xhT[((gb*4+h)*32 + kin)][n] bf16, pack 4 consecutive n per store
#pragma unroll
  for (int jj = 0; jj < 4; ++jj) {
    const int kin = k4i + jj;
    ushort4 u;
    u.x = bfbits(acc[0][jj]); u.y = bfbits(acc[1][jj]);
    u.z = bfbits(acc[2][jj]); u.w = bfbits(acc[3][jj]);
    *(ushort4*)&xhT[((gb * 4 + h) * 32 + kin) * NN + n0] = u;
  }
#pragma unroll
  for (int s = 1; s < 8; s <<= 1) {
#pragma unroll
    for (int ii = 0; ii < 4; ++ii) {
      p1[ii] += __shfl_xor(p1[ii], s);
      p2[ii] += __shfl_xor(p2[ii], s);
    }
  }
  if ((og & 7) == 0) {
#pragma unroll
    for (int ii = 0; ii < 4; ++ii) {
      s1[(gb * 4 + h) * NN + n0 + ii] = p1[ii];
      s2[(gb * 4 + h) * NN + n0 + ii] = p2[ii];
    }
  }
}

// ---------------------------------------------------------------------------
// K3: GAT attention via MFMA. block = (g,b, 32-row i-tile); wave = head.
// P built in-register as the MFMA A-fragment; adjacency ballot-packed to LDS.
// ---------------------------------------------------------------------------
__global__ __launch_bounds__(256) void k3_attn(const unsigned short* __restrict__ xhT,
                                               const float* __restrict__ s1w,
                                               const float* __restrict__ s2w,
                                               const int* __restrict__ adjA,
                                               const int* __restrict__ adjB,
                                               const float* __restrict__ attb,
                                               const float* __restrict__ x,
                                               float* __restrict__ G) {
  __shared__ unsigned int adjL[32][66];  // stride 66 words: bank=(2i+w)%32, <=2-way (free)
  __shared__ float s2L[4][2048];         // pre-scaled by LOG2E
  __shared__ float denL[4][32];
  const int t = threadIdx.x;
  const int wave = t >> 6, lane = t & 63;
  const int blk = blockIdx.x;
  const int g = blk >> 8, b = (blk >> 6) & 3;
  const int i0 = (blk & 63) * 32;
  const int gb = g * 4 + b;
  const int* adj = (g ? adjB : adjA) + (b * NN + i0) * NN;
  // ---- stage s2 * LOG2E for all 4 heads ----
  {
    const float* s2g = s2w + gb * 4 * NN;
    float* s2f = &s2L[0][0];
#pragma unroll
    for (int u = 0; u < 8; ++u) {
      const int idx = u * 1024 + t * 4;
      float4 v = *(const float4*)&s2g[idx];
      v.x *= LOG2E; v.y *= LOG2E; v.z *= LOG2E; v.w *= LOG2E;
      *(float4*)&s2f[idx] = v;
    }
  }
  // ---- ballot-pack 32 adjacency rows into LDS bitmask (read ints once) ----
  for (int r8 = 0; r8 < 8; ++r8) {
    const int r = wave * 8 + r8;
    const int* arow = adj + r * NN;
#pragma unroll 4
    for (int w = 0; w < 32; ++w) {
      const int av = arow[w * 64 + lane];
      const unsigned long long m = __ballot(av > 0);
      if (lane < 2) adjL[r][2 * w + lane] = (unsigned int)(m >> (32 * lane));
    }
  }
  __syncthreads();

  const int h = wave;
  const int i = lane & 31;       // A row / D col index
  const int jslot = lane >> 5;
  const float sc1v = (s1w[(gb * 4 + h) * NN + i0 + i] + attb[h]) * LOG2E;
  const unsigned short* bptr = xhT + ((gb * 4 + h) * 32 + i) * NN;  // col = lane&31
  f32x16 acc = {0.f, 0.f, 0.f, 0.f, 0.f, 0.f, 0.f, 0.f,
                0.f, 0.f, 0.f, 0.f, 0.f, 0.f, 0.f, 0.f};
  float den = 0.f;
#pragma unroll 2
  for (int jb = 0; jb < NN; jb += 32) {
    const unsigned int wbits = adjL[i][jb >> 5];
#pragma unroll
    for (int half = 0; half < 2; ++half) {
      const int j0 = jb + half * 16 + jslot * 8;
      const float4 s2a = *(const float4*)&s2L[h][j0];
      const float4 s2b = *(const float4*)&s2L[h][j0 + 4];
      const unsigned int bits8 = wbits >> (half * 16 + jslot * 8);
      const float sv[8] = {s2a.x, s2a.y, s2a.z, s2a.w, s2b.x, s2b.y, s2b.z, s2b.w};
      union { bf16x8 v; unsigned short u[8]; } af;
#pragma unroll
      for (int e = 0; e < 8; ++e) {
        float s = sc1v + sv[e];
        s = fmaxf(s, NEG * s);                     // leaky (scale-invariant)
        float pe = __builtin_amdgcn_exp2f(s);
        pe = ((bits8 >> e) & 1u) ? pe : 0.f;
        const unsigned short ub = bfbits(pe);
        af.u[e] = ub;
        union { unsigned int w; float f; } bk;     // bf16 -> f32 for denominator
        bk.w = ((unsigned int)ub) << 16;
        den += bk.f;
      }
      const bf16x8 bf = *(const bf16x8*)&bptr[j0];
      acc = __builtin_amdgcn_mfma_f32_32x32x16_bf16(af.v, bf, acc, 0, 0, 0);
    }
  }
  den += __shfl_xor(den, 32);
  if (lane < 32) denL[h][lane] = den;
  __syncthreads();
  // D layout (32x32): col = lane&31, row = (reg&3) + 8*(reg>>2) + 4*(lane>>5)
#pragma unroll
  for (int r = 0; r < 16; ++r) {
    const int row = (r & 3) + 8 * (r >> 2) + 4 * jslot;
    const float dinv = 1.f / denL[h][row];
    const int off = (gb * NN + i0 + row) * 128 + h * 32 + i;
    G[off] = fmaxf(acc[r] * dinv, 0.f) + x[off];
  }
}

// ---------------------------------------------------------------------------
// K4h: per (g,b): hv = GGE(in); e[gb][0:128] = hv; hvbuf[gb] = hv
// ---------------------------------------------------------------------------
__global__ __launch_bounds__(256) void k4h_gge(const float* __restrict__ a_in,
                                               const float* __restrict__ b_in,
                                               const float* __restrict__ ggeW1,
                                               const float* __restrict__ ggeb1,
                                               const float* __restrict__ ggeW2,
                                               const float* __restrict__ ggeb2,
                                               float* __restrict__ hvbuf,
                                               float* __restrict__ e) {
  __shared__ float inL[512];
  __shared__ float h1L[128];
  const int t = threadIdx.x;
  const int wave = t >> 6, lane = t & 63;
  const int g = blockIdx.x >> 2, b = blockIdx.x & 3;
  const int gb2 = g * 4 + b;
  const float* inp = (g ? b_in : a_in) + b * 512;
  if (t < 128) *(float4*)&inL[t * 4] = *(const float4*)&inp[t * 4];
  __syncthreads();
  for (int p = 0; p < 16; ++p) {
    const int o0 = p * 8 + wave * 2;
    const float* w0 = &ggeW1[o0 * 512 + lane * 8];
    const float* w1 = &ggeW1[(o0 + 1) * 512 + lane * 8];
    const float4 i0v = *(const float4*)&inL[lane * 8];
    const float4 i1v = *(const float4*)&inL[lane * 8 + 4];
    float s0 = dot4(*(const float4*)&w0[0], i0v) + dot4(*(const float4*)&w0[4], i1v);
    float s1v = dot4(*(const float4*)&w1[0], i0v) + dot4(*(const float4*)&w1[4], i1v);
#pragma unroll
    for (int s = 1; s < 64; s <<= 1) { s0 += __shfl_xor(s0, s); s1v += __shfl_xor(s1v, s); }
    if (lane == 0) {
      h1L[o0] = fmaxf(s0 + ggeb1[o0], 0.f);
      h1L[o0 + 1] = fmaxf(s1v + ggeb1[o0 + 1], 0.f);
    }
  }
  __syncthreads();
  for (int p = 0; p < 16; ++p) {
    const int o0 = p * 8 + wave * 2;
    const float2 w0 = *(const float2*)&ggeW2[o0 * 128 + lane * 2];
    const float2 w1 = *(const float2*)&ggeW2[(o0 + 1) * 128 + lane * 2];
    const float2 hvv = *(const float2*)&h1L[lane * 2];
    float s0 = w0.x * hvv.x + w0.y * hvv.y;
    float s1v = w1.x * hvv.x + w1.y * hvv.y;
#pragma unroll
    for (int s = 1; s < 64; s <<= 1) { s0 += __shfl_xor(s0, s); s1v += __shfl_xor(s1v, s); }
    if (lane == 0) {
      const float v0 = fmaxf(s0 + ggeb2[o0], 0.f);
      const float v1 = fmaxf(s1v + ggeb2[o0 + 1], 0.f);
      hvbuf[gb2 * 128 + o0] = v0;
      hvbuf[gb2 * 128 + o0 + 1] = v1;
      e[gb2 * 256 + o0] = v0;
      e[gb2 * 256 + o0 + 1] = v1;
    }
  }
}

// ---------------------------------------------------------------------------
// K4a: GAGA logits lg[gb][n] = G[n,:].hv   grid = gb*16 chunks
// ---------------------------------------------------------------------------
__global__ __launch_bounds__(256) void k4a_logits(const float* __restrict__ G,
                                                  const float* __restrict__ hv,
                                                  float* __restrict__ lg) {
  const int t = threadIdx.x;
  const int wave = t >> 6, lane = t & 63;
  const int gb = blockIdx.x >> 4, chunk = blockIdx.x & 15;
  const float2 hvv = *(const float2*)&hv[gb * 128 + lane * 2];
  const float* Gb = G + gb * NN * 128;
  const int nbase = chunk * 128 + wave * 32;
  for (int q = 0; q < 32; ++q) {
    const int n = nbase + q;
    const float2 gv = *(const float2*)&Gb[n * 128 + lane * 2];
    float part = gv.x * hvv.x + gv.y * hvv.y;
#pragma unroll
    for (int s = 1; s < 64; s <<= 1) part += __shfl_xor(part, s);
    if (lane == 0) lg[gb * NN + n] = part;
  }
}

// ---------------------------------------------------------------------------
// K4b: per gb: max and Z over 2048 logits
// ---------------------------------------------------------------------------
__global__ __launch_bounds__(256) void k4b_reduce(const float* __restrict__ lg,
                                                  float* __restrict__ mz) {
  __shared__ float red[256];
  const int t = threadIdx.x;
  const int gb = blockIdx.x;
  const float* l = lg + gb * NN;
  float m = -1e30f;
  for (int n = t; n < NN; n += 256) m = fmaxf(m, l[n]);
  red[t] = m; __syncthreads();
#pragma unroll
  for (int s = 128; s > 0; s >>= 1) {
    if (t < s) red[t] = fmaxf(red[t], red[t + s]);
    __syncthreads();
  }
  const float mx = red[0]; __syncthreads();
  float z = 0.f;
  for (int n = t; n < NN; n += 256) z += __expf(l[n] - mx);
  red[t] = z; __syncthreads();
#pragma unroll
  for (int s = 128; s > 0; s >>= 1) {
    if (t < s) red[t] += red[t + s];
    __syncthreads();
  }
  if (t == 0) { mz[gb * 2] = mx; mz[gb * 2 + 1] = red[0]; }
}

// ---------------------------------------------------------------------------
// K4c: partial weighted sums wsum[gb][chunk][128] over 128-n chunks
// ---------------------------------------------------------------------------
__global__ __launch_bounds__(256) void k4c_wsum(const float* __restrict__ G,
                                                const float* __restrict__ lg,
                                                const float* __restrict__ mz,
                                                float* __restrict__ wsum) {
  __shared__ float pL[128];
  __shared__ float red[2][128];
  const int t = threadIdx.x;
  const int gb = blockIdx.x >> 4, chunk = blockIdx.x & 15;
  const float mx = mz[gb * 2];
  if (t < 128) pL[t] = __expf(lg[gb * NN + chunk * 128 + t] - mx);
  __syncthreads();
  const int d = t & 127, half = t >> 7;
  const float* Gb = G + (gb * NN + chunk * 128 + half * 64) * 128;
  float acc = 0.f;
  for (int q = 0; q < 64; ++q) acc += pL[half * 64 + q] * Gb[q * 128 + d];
  red[half][d] = acc;
  __syncthreads();
  if (t < 128) wsum[(gb * 16 + chunk) * 128 + t] = red[0][t] + red[1][t];
}

// ---------------------------------------------------------------------------
// K4d: e[gb][128+d] = sum_chunk wsum / Z
// ---------------------------------------------------------------------------
__global__ __launch_bounds__(128) void k4d_final(const float* __restrict__ wsum,
                                                 const float* __restrict__ mz,
                                                 float* __restrict__ e) {
  const int t = threadIdx.x;
  const int gb = blockIdx.x;
  float s = 0.f;
#pragma unroll
  for (int c = 0; c < 16; ++c) s += wsum[(gb * 16 + c) * 128 + t];
  e[gb * 256 + 128 + t] = s / mz[gb * 2 + 1];
}

// ---------------------------------------------------------------------------
// K5: LED head per batch
// ---------------------------------------------------------------------------
__global__ __launch_bounds__(256) void k5_led(const float* __restrict__ e,
                                              const float* __restrict__ convW,
                                              const float* __restrict__ convb,
                                              const float* __restrict__ ledW1,
                                              const float* __restrict__ ledb1,
                                              const float* __restrict__ ledW2,
                                              const float* __restrict__ ledb2,
                                              float* __restrict__ out) {
  __shared__ float eaL[256], ebL[256], uL[512], xL[128], lgL[2];
  const int t = threadIdx.x;
  const int wave = t >> 6, lane = t & 63;
  const int bt = blockIdx.x;
  if (t < 64) {
    *(float4*)&eaL[t * 4] = *(const float4*)&e[bt * 256 + t * 4];
    *(float4*)&ebL[t * 4] = *(const float4*)&e[(4 + bt) * 256 + t * 4];
  }
  __syncthreads();
  uL[256 + t] = eaL[t] - ebL[t];
  const float4 ea4 = *(const float4*)&eaL[lane * 4];
  const float4 eb4 = *(const float4*)&ebL[lane * 4];
  for (int p = 0; p < 32; ++p) {
    const int o0 = p * 8 + wave * 2;
    const float4 w0 = *(const float4*)&convW[o0 * 256 + lane * 4];
    const float4 w1 = *(const float4*)&convW[(o0 + 1) * 256 + lane * 4];
    float sa0 = dot4(w0, ea4), sb0 = dot4(w0, eb4);
    float sa1 = dot4(w1, ea4), sb1 = dot4(w1, eb4);
#pragma unroll
    for (int s = 1; s < 64; s <<= 1) {
      sa0 += __shfl_xor(sa0, s); sb0 += __shfl_xor(sb0, s);
      sa1 += __shfl_xor(sa1, s); sb1 += __shfl_xor(sb1, s);
    }
    if (lane == 0) {
      const float c0 = convb[o0], c1 = convb[o0 + 1];
      uL[o0] = fmaxf(sa0 + c0, sb0 + c0);
      uL[o0 + 1] = fmaxf(sa1 + c1, sb1 + c1);
    }
  }
  __syncthreads();
  for (int p = 0; p < 16; ++p) {
    const int o0 = p * 8 + wave * 2;
    const float* w0 = &ledW1[o0 * 512 + lane * 8];
    const float* w1 = &ledW1[(o0 + 1) * 512 + lane * 8];
    const float4 u0 = *(const float4*)&uL[lane * 8];
    const float4 u1 = *(const float4*)&uL[lane * 8 + 4];
    float s0 = dot4(*(const float4*)&w0[0], u0) + dot4(*(const float4*)&w0[4], u1);
    float s1v = dot4(*(const float4*)&w1[0], u0) + dot4(*(const float4*)&w1[4], u1);
#pragma unroll
    for (int s = 1; s < 64; s <<= 1) { s0 += __shfl_xor(s0, s); s1v += __shfl_xor(s1v, s); }
    if (lane == 0) {
      xL[o0] = fmaxf(s0 + ledb1[o0], 0.f);
      xL[o0 + 1] = fmaxf(s1v + ledb1[o0 + 1], 0.f);
    }
  }
  __syncthreads();
  if (wave < 2) {
    const float2 w = *(const float2*)&ledW2[wave * 128 + lane * 2];
    const float2 xv = *(const float2*)&xL[lane * 2];
    float s0 = w.x * xv.x + w.y * xv.y;
#pragma unroll
    for (int s = 1; s < 64; s <<= 1) s0 += __shfl_xor(s0, s);
    if (lane == 0) lgL[wave] = s0 + ledb2[wave];
  }
  __syncthreads();
  if (t == 0) {
    const float l0 = lgL[0], l1 = lgL[1];
    const float m = fmaxf(l0, l1);
    const float za = __expf(l0 - m) + __expf(l1 - m);
    const float lz = __logf(za);
    out[bt * 2 + 0] = l0 - m - lz;
    out[bt * 2 + 1] = l1 - m - lz;
  }
}

// ---------------------------------------------------------------------------
extern "C" void kernel_launch(void* const* d_in, const int* in_sizes, int n_in,
                              void* d_out, int out_size, void* d_ws, size_t ws_size,
                              hipStream_t stream) {
  (void)in_sizes; (void)n_in; (void)out_size; (void)ws_size;
  const float* a     = (const float*)d_in[0];
  const float* bioA  = (const float*)d_in[1];
  const int*   A     = (const int*)d_in[2];
  const float* b     = (const float*)d_in[3];
  const float* bioB  = (const float*)d_in[4];
  const int*   B     = (const int*)d_in[5];
  const float* initW = (const float*)d_in[6];
  const float* initb = (const float*)d_in[7];
  const float* projW = (const float*)d_in[8];
  const float* attw  = (const float*)d_in[9];
  const float* attb  = (const float*)d_in[10];
  const float* ggeW1 = (const float*)d_in[11];
  const float* ggeb1 = (const float*)d_in[12];
  const float* ggeW2 = (const float*)d_in[13];
  const float* ggeb2 = (const float*)d_in[14];
  const float* convW = (const float*)d_in[15];
  const float* convb = (const float*)d_in[16];
  const float* ledW1 = (const float*)d_in[17];
  const float* ledb1 = (const float*)d_in[18];
  const float* ledW2 = (const float*)d_in[19];
  const float* ledb2 = (const float*)d_in[20];

  float* ws = (float*)d_ws;
  float*          x    = ws;                           // 2,097,152 f32
  unsigned short* xhT  = (unsigned short*)(ws + 2097152); // 2,097,152 u16 (=1,048,576 f32)
  float*          s1   = ws + 3145728;                 // 65,536
  float*          s2   = ws + 3211264;                 // 65,536
  float*          G    = ws + 3276800;                 // 2,097,152
  float*          lg   = ws + 5373952;                 // 16,384
  float*          wsum = ws + 5390336;                 // 16,384
  float*          mz   = ws + 5406720;                 // 16
  float*          hv   = ws + 5406736;                 // 1,024
  float*          e    = ws + 5407760;                 // 2,048
  float* out = (float*)d_out;

  k1_init<<<512, 256, 0, stream>>>(bioA, bioB, initW, initb, x);
  k2_proj<<<512, 256, 0, stream>>>(x, projW, attw, xhT, s1, s2);
  k3_attn<<<512, 256, 0, stream>>>(xhT, s1, s2, A, B, attb, x, G);
  k4h_gge<<<8, 256, 0, stream>>>(a, b, ggeW1, ggeb1, ggeW2, ggeb2, hv, e);
  k4a_logits<<<128, 256, 0, stream>>>(G, hv, lg);
  k4b_reduce<<<8, 256, 0, stream>>>(lg, mz);
  k4c_wsum<<<128, 256, 0, stream>>>(G, lg, mz, wsum);
  k4d_final<<<8, 128, 0, stream>>>(wsum, mz, e);
  k5_led<<<4, 256, 0, stream>>>(e, convW, convb, ledW1, ledb1, ledW2, ledb2, out);
}

// Round 3
// 200.032 us; speedup vs baseline: 2.7332x; 1.1773x over previous
//
#include <hip/hip_runtime.h>
#include <hip/hip_bf16.h>
#include <math.h>

#define NN 2048
#define NEG 0.2f
#define LOG2E 1.44269504f

typedef short bf16x8 __attribute__((ext_vector_type(8)));
typedef float f32x16 __attribute__((ext_vector_type(16)));

__device__ __forceinline__ float dot4(float4 a, float4 b) {
  return a.x * b.x + a.y * b.y + a.z * b.z + a.w * b.w;
}

__device__ __forceinline__ unsigned short bfbits(float f) {
  union { __hip_bfloat16 b; unsigned short u; } c;
  c.b = __float2bfloat16(f);
  return c.u;
}

// ---------------------------------------------------------------------------
// K1: x = bio @ initW^T + initb      rows = [g][b][n] (16384), K=256, out 128
// ---------------------------------------------------------------------------
__global__ __launch_bounds__(256) void k1_init(const float* __restrict__ bioA,
                                               const float* __restrict__ bioB,
                                               const float* __restrict__ W,
                                               const float* __restrict__ bias,
                                               float* __restrict__ xout) {
  __shared__ float As[32][36];
  __shared__ float Ws[32][132];
  const int t = threadIdx.x;
  const int m0 = blockIdx.x * 32;
  const float* A = (m0 < 8192) ? bioA : bioB;
  const int arow0 = (m0 < 8192) ? m0 : (m0 - 8192);
  const int og = t & 31, ig = t >> 5;
  float acc[4][4] = {};
  for (int kt = 0; kt < 256; kt += 32) {
    __syncthreads();
    {
      const int r = t >> 3, kq = t & 7;
      const float4 v = *(const float4*)&A[(arow0 + r) * 256 + kt + kq * 4];
      As[kq * 4 + 0][r] = v.x; As[kq * 4 + 1][r] = v.y;
      As[kq * 4 + 2][r] = v.z; As[kq * 4 + 3][r] = v.w;
    }
#pragma unroll
    for (int u = 0; u < 4; ++u) {
      const int f = u * 256 + t;
      const int o = f >> 3, kq = f & 7;
      const float4 v = *(const float4*)&W[o * 256 + kt + kq * 4];
      Ws[kq * 4 + 0][o] = v.x; Ws[kq * 4 + 1][o] = v.y;
      Ws[kq * 4 + 2][o] = v.z; Ws[kq * 4 + 3][o] = v.w;
    }
    __syncthreads();
#pragma unroll
    for (int kk = 0; kk < 32; ++kk) {
      const float4 a4 = *(const float4*)&As[kk][ig * 4];
      const float4 w4 = *(const float4*)&Ws[kk][og * 4];
      const float av[4] = {a4.x, a4.y, a4.z, a4.w};
      const float wv[4] = {w4.x, w4.y, w4.z, w4.w};
#pragma unroll
      for (int ii = 0; ii < 4; ++ii)
#pragma unroll
        for (int jj = 0; jj < 4; ++jj) acc[ii][jj] += av[ii] * wv[jj];
    }
  }
  const float4 b4 = *(const float4*)&bias[og * 4];
#pragma unroll
  for (int ii = 0; ii < 4; ++ii) {
    const int row = m0 + ig * 4 + ii;
    float4 o4;
    o4.x = acc[ii][0] + b4.x; o4.y = acc[ii][1] + b4.y;
    o4.z = acc[ii][2] + b4.z; o4.w = acc[ii][3] + b4.w;
    *(float4*)&xout[row * 128 + og * 4] = o4;
  }
}

// ---------------------------------------------------------------------------
// K2: y = x @ projW^T ; write xhT bf16 [gb][h][k=32][n=2048] ; s1,s2 f32
// ---------------------------------------------------------------------------
__global__ __launch_bounds__(256) void k2_proj(const float* __restrict__ x,
                                               const float* __restrict__ W,
                                               const float* __restrict__ attw,
                                               unsigned short* __restrict__ xhT,
                                               float* __restrict__ s1,
                                               float* __restrict__ s2) {
  __shared__ float As[32][36];
  __shared__ float Ws[32][132];
  const int t = threadIdx.x;
  const int m0 = blockIdx.x * 32;
  const int og = t & 31, ig = t >> 5;
  float acc[4][4] = {};
  for (int kt = 0; kt < 128; kt += 32) {
    __syncthreads();
    {
      const int r = t >> 3, kq = t & 7;
      const float4 v = *(const float4*)&x[(m0 + r) * 128 + kt + kq * 4];
      As[kq * 4 + 0][r] = v.x; As[kq * 4 + 1][r] = v.y;
      As[kq * 4 + 2][r] = v.z; As[kq * 4 + 3][r] = v.w;
    }
#pragma unroll
    for (int u = 0; u < 4; ++u) {
      const int f = u * 256 + t;
      const int o = f >> 3, kq = f & 7;
      const float4 v = *(const float4*)&W[o * 128 + kt + kq * 4];
      Ws[kq * 4 + 0][o] = v.x; Ws[kq * 4 + 1][o] = v.y;
      Ws[kq * 4 + 2][o] = v.z; Ws[kq * 4 + 3][o] = v.w;
    }
    __syncthreads();
#pragma unroll
    for (int kk = 0; kk < 32; ++kk) {
      const float4 a4 = *(const float4*)&As[kk][ig * 4];
      const float4 w4 = *(const float4*)&Ws[kk][og * 4];
      const float av[4] = {a4.x, a4.y, a4.z, a4.w};
      const float wv[4] = {w4.x, w4.y, w4.z, w4.w};
#pragma unroll
      for (int ii = 0; ii < 4; ++ii)
#pragma unroll
        for (int jj = 0; jj < 4; ++jj) acc[ii][jj] += av[ii] * wv[jj];
    }
  }
  const int h = og >> 3;
  const int k4i = (og & 7) * 4;
  const int g = m0 >> 13;
  const int bb = (m0 >> 11) & 3;
  const int gb = g * 4 + bb;
  const int n0 = (m0 & 2047) + ig * 4;
  const float4 w1 = *(const float4*)&attw[h * 64 + k4i];
  const float4 w2 = *(const float4*)&attw[h * 64 + 32 + k4i];
  float p1[4], p2[4];
#pragma unroll
  for (int ii = 0; ii < 4; ++ii) {
    float4 v;
    v.x = acc[ii][0]; v.y = acc[ii][1]; v.z = acc[ii][2]; v.w = acc[ii][3];
    p1[ii] = dot4(v, w1);
    p2[ii] = dot4(v, w2);
  }
#pragma unroll
  for (int jj = 0; jj < 4; ++jj) {
    const int kin = k4i + jj;
    ushort4 u;
    u.x = bfbits(acc[0][jj]); u.y = bfbits(acc[1][jj]);
    u.z = bfbits(acc[2][jj]); u.w = bfbits(acc[3][jj]);
    *(ushort4*)&xhT[((gb * 4 + h) * 32 + kin) * NN + n0] = u;
  }
#pragma unroll
  for (int s = 1; s < 8; s <<= 1) {
#pragma unroll
    for (int ii = 0; ii < 4; ++ii) {
      p1[ii] += __shfl_xor(p1[ii], s);
      p2[ii] += __shfl_xor(p2[ii], s);
    }
  }
  if ((og & 7) == 0) {
#pragma unroll
    for (int ii = 0; ii < 4; ++ii) {
      s1[(gb * 4 + h) * NN + n0 + ii] = p1[ii];
      s2[(gb * 4 + h) * NN + n0 + ii] = p2[ii];
    }
  }
}

// ---------------------------------------------------------------------------
// K3: GAT attention via MFMA. block = (g,b, 32-row i-tile), 512 threads.
// wave = (jhalf, head): jhalf waves split the 2048-j loop; partials merged
// via LDS. P built in-register as MFMA A-frag; adjacency ballot-packed.
// ---------------------------------------------------------------------------
__global__ __launch_bounds__(512) void k3_attn(const unsigned short* __restrict__ xhT,
                                               const float* __restrict__ s1w,
                                               const float* __restrict__ s2w,
                                               const int* __restrict__ adjA,
                                               const int* __restrict__ adjB,
                                               const float* __restrict__ attb,
                                               const float* __restrict__ x,
                                               float* __restrict__ G) {
  __shared__ unsigned int adjL[32][66];  // stride 66 words: <=2-way alias (free)
  __shared__ float s2L[4][2048];         // pre-scaled by LOG2E
  __shared__ float accR[4][16][65];      // jhalf=1 partial acc, +1 pad
  __shared__ float denR[4][2][32];
  const int t = threadIdx.x;
  const int wave = t >> 6, lane = t & 63;
  const int blk = blockIdx.x;
  const int g = blk >> 8, b = (blk >> 6) & 3;
  const int i0 = (blk & 63) * 32;
  const int gb = g * 4 + b;
  const int* adj = (g ? adjB : adjA) + (b * NN + i0) * NN;
  // ---- stage s2 * LOG2E for all 4 heads (8192 floats, 512 threads) ----
  {
    const float* s2g = s2w + gb * 4 * NN;
    float* s2f = &s2L[0][0];
#pragma unroll
    for (int u = 0; u < 4; ++u) {
      const int idx = u * 2048 + t * 4;
      float4 v = *(const float4*)&s2g[idx];
      v.x *= LOG2E; v.y *= LOG2E; v.z *= LOG2E; v.w *= LOG2E;
      *(float4*)&s2f[idx] = v;
    }
  }
  // ---- ballot-pack 32 adjacency rows into LDS bitmask (4 rows/wave) ----
#pragma unroll
  for (int r4 = 0; r4 < 4; ++r4) {
    const int r = wave * 4 + r4;
    const int* arow = adj + r * NN;
#pragma unroll 4
    for (int w = 0; w < 32; ++w) {
      const int av = arow[w * 64 + lane];
      const unsigned long long m = __ballot(av > 0);
      if (lane < 2) adjL[r][2 * w + lane] = (unsigned int)(m >> (32 * lane));
    }
  }
  __syncthreads();

  const int h = wave & 3;
  const int jhalf = wave >> 2;
  const int jlo = jhalf * 1024;
  const int i = lane & 31;       // A row / D col index
  const int jslot = lane >> 5;
  const float sc1v = (s1w[(gb * 4 + h) * NN + i0 + i] + attb[h]) * LOG2E;
  const unsigned short* bptr = xhT + ((gb * 4 + h) * 32 + i) * NN;
  f32x16 acc = {0.f, 0.f, 0.f, 0.f, 0.f, 0.f, 0.f, 0.f,
                0.f, 0.f, 0.f, 0.f, 0.f, 0.f, 0.f, 0.f};
  float den = 0.f;
  bf16x8 bf_cur = *(const bf16x8*)&bptr[jlo + jslot * 8];
  for (int jb = jlo; jb < jlo + 1024; jb += 32) {
    const unsigned int wbits = adjL[i][jb >> 5];
#pragma unroll
    for (int half = 0; half < 2; ++half) {
      const int j0 = jb + half * 16 + jslot * 8;
      // prefetch next half's B-frag (final iter overreads <=16B into ws: safe)
      const bf16x8 bf_next = *(const bf16x8*)&bptr[j0 + 16];
      const float4 s2a = *(const float4*)&s2L[h][j0];
      const float4 s2b = *(const float4*)&s2L[h][j0 + 4];
      const unsigned int bits8 = wbits >> (half * 16 + jslot * 8);
      const float sv[8] = {s2a.x, s2a.y, s2a.z, s2a.w, s2b.x, s2b.y, s2b.z, s2b.w};
      union { bf16x8 v; unsigned short u[8]; } af;
#pragma unroll
      for (int e = 0; e < 8; ++e) {
        float s = sc1v + sv[e];
        s = fmaxf(s, NEG * s);                     // leaky (scale-invariant)
        float pe = __builtin_amdgcn_exp2f(s);
        pe = ((bits8 >> e) & 1u) ? pe : 0.f;
        af.u[e] = bfbits(pe);
        den += pe;                                  // f32 denominator
      }
      acc = __builtin_amdgcn_mfma_f32_32x32x16_bf16(af.v, bf_cur, acc, 0, 0, 0);
      bf_cur = bf_next;
    }
  }
  den += __shfl_xor(den, 32);
  if (lane < 32) denR[h][jhalf][lane] = den;
  if (jhalf == 1) {
#pragma unroll
    for (int r = 0; r < 16; ++r) accR[h][r][lane] = acc[r];
  }
  __syncthreads();
  if (jhalf == 0) {
    // D layout (32x32): col = lane&31, row = (reg&3) + 8*(reg>>2) + 4*(lane>>5)
#pragma unroll
    for (int r = 0; r < 16; ++r) {
      const int row = (r & 3) + 8 * (r >> 2) + 4 * jslot;
      const float dinv = 1.f / (denR[h][0][row] + denR[h][1][row]);
      const int off = (gb * NN + i0 + row) * 128 + h * 32 + i;
      const float av = acc[r] + accR[h][r][lane];
      G[off] = fmaxf(av * dinv, 0.f) + x[off];
    }
  }
}

// ---------------------------------------------------------------------------
// K4h: per (g,b): hv = GGE(in); e[gb][0:128] = hv; hvbuf[gb] = hv
// ---------------------------------------------------------------------------
__global__ __launch_bounds__(256) void k4h_gge(const float* __restrict__ a_in,
                                               const float* __restrict__ b_in,
                                               const float* __restrict__ ggeW1,
                                               const float* __restrict__ ggeb1,
                                               const float* __restrict__ ggeW2,
                                               const float* __restrict__ ggeb2,
                                               float* __restrict__ hvbuf,
                                               float* __restrict__ e) {
  __shared__ float inL[512];
  __shared__ float h1L[128];
  const int t = threadIdx.x;
  const int wave = t >> 6, lane = t & 63;
  const int g = blockIdx.x >> 2, b = blockIdx.x & 3;
  const int gb2 = g * 4 + b;
  const float* inp = (g ? b_in : a_in) + b * 512;
  if (t < 128) *(float4*)&inL[t * 4] = *(const float4*)&inp[t * 4];
  __syncthreads();
  for (int p = 0; p < 16; ++p) {
    const int o0 = p * 8 + wave * 2;
    const float* w0 = &ggeW1[o0 * 512 + lane * 8];
    const float* w1 = &ggeW1[(o0 + 1) * 512 + lane * 8];
    const float4 i0v = *(const float4*)&inL[lane * 8];
    const float4 i1v = *(const float4*)&inL[lane * 8 + 4];
    float s0 = dot4(*(const float4*)&w0[0], i0v) + dot4(*(const float4*)&w0[4], i1v);
    float s1v = dot4(*(const float4*)&w1[0], i0v) + dot4(*(const float4*)&w1[4], i1v);
#pragma unroll
    for (int s = 1; s < 64; s <<= 1) { s0 += __shfl_xor(s0, s); s1v += __shfl_xor(s1v, s); }
    if (lane == 0) {
      h1L[o0] = fmaxf(s0 + ggeb1[o0], 0.f);
      h1L[o0 + 1] = fmaxf(s1v + ggeb1[o0 + 1], 0.f);
    }
  }
  __syncthreads();
  for (int p = 0; p < 16; ++p) {
    const int o0 = p * 8 + wave * 2;
    const float2 w0 = *(const float2*)&ggeW2[o0 * 128 + lane * 2];
    const float2 w1 = *(const float2*)&ggeW2[(o0 + 1) * 128 + lane * 2];
    const float2 hvv = *(const float2*)&h1L[lane * 2];
    float s0 = w0.x * hvv.x + w0.y * hvv.y;
    float s1v = w1.x * hvv.x + w1.y * hvv.y;
#pragma unroll
    for (int s = 1; s < 64; s <<= 1) { s0 += __shfl_xor(s0, s); s1v += __shfl_xor(s1v, s); }
    if (lane == 0) {
      const float v0 = fmaxf(s0 + ggeb2[o0], 0.f);
      const float v1 = fmaxf(s1v + ggeb2[o0 + 1], 0.f);
      hvbuf[gb2 * 128 + o0] = v0;
      hvbuf[gb2 * 128 + o0 + 1] = v1;
      e[gb2 * 256 + o0] = v0;
      e[gb2 * 256 + o0 + 1] = v1;
    }
  }
}

// ---------------------------------------------------------------------------
// K4a: GAGA logits lg[gb][n] = G[n,:].hv   grid = gb*16 chunks
// ---------------------------------------------------------------------------
__global__ __launch_bounds__(256) void k4a_logits(const float* __restrict__ G,
                                                  const float* __restrict__ hv,
                                                  float* __restrict__ lg) {
  const int t = threadIdx.x;
  const int wave = t >> 6, lane = t & 63;
  const int gb = blockIdx.x >> 4, chunk = blockIdx.x & 15;
  const float2 hvv = *(const float2*)&hv[gb * 128 + lane * 2];
  const float* Gb = G + gb * NN * 128;
  const int nbase = chunk * 128 + wave * 32;
  for (int q = 0; q < 32; ++q) {
    const int n = nbase + q;
    const float2 gv = *(const float2*)&Gb[n * 128 + lane * 2];
    float part = gv.x * hvv.x + gv.y * hvv.y;
#pragma unroll
    for (int s = 1; s < 64; s <<= 1) part += __shfl_xor(part, s);
    if (lane == 0) lg[gb * NN + n] = part;
  }
}

// ---------------------------------------------------------------------------
// K4b: per gb: max and Z over 2048 logits
// ---------------------------------------------------------------------------
__global__ __launch_bounds__(256) void k4b_reduce(const float* __restrict__ lg,
                                                  float* __restrict__ mz) {
  __shared__ float red[256];
  const int t = threadIdx.x;
  const int gb = blockIdx.x;
  const float* l = lg + gb * NN;
  float m = -1e30f;
  for (int n = t; n < NN; n += 256) m = fmaxf(m, l[n]);
  red[t] = m; __syncthreads();
#pragma unroll
  for (int s = 128; s > 0; s >>= 1) {
    if (t < s) red[t] = fmaxf(red[t], red[t + s]);
    __syncthreads();
  }
  const float mx = red[0]; __syncthreads();
  float z = 0.f;
  for (int n = t; n < NN; n += 256) z += __expf(l[n] - mx);
  red[t] = z; __syncthreads();
#pragma unroll
  for (int s = 128; s > 0; s >>= 1) {
    if (t < s) red[t] += red[t + s];
    __syncthreads();
  }
  if (t == 0) { mz[gb * 2] = mx; mz[gb * 2 + 1] = red[0]; }
}

// ---------------------------------------------------------------------------
// K4c: partial weighted sums wsum[gb][chunk][128] over 128-n chunks
// ---------------------------------------------------------------------------
__global__ __launch_bounds__(256) void k4c_wsum(const float* __restrict__ G,
                                                const float* __restrict__ lg,
                                                const float* __restrict__ mz,
                                                float* __restrict__ wsum) {
  __shared__ float pL[128];
  __shared__ float red[2][128];
  const int t = threadIdx.x;
  const int gb = blockIdx.x >> 4, chunk = blockIdx.x & 15;
  const float mx = mz[gb * 2];
  if (t < 128) pL[t] = __expf(lg[gb * NN + chunk * 128 + t] - mx);
  __syncthreads();
  const int d = t & 127, half = t >> 7;
  const float* Gb = G + (gb * NN + chunk * 128 + half * 64) * 128;
  float acc = 0.f;
  for (int q = 0; q < 64; ++q) acc += pL[half * 64 + q] * Gb[q * 128 + d];
  red[half][d] = acc;
  __syncthreads();
  if (t < 128) wsum[(gb * 16 + chunk) * 128 + t] = red[0][t] + red[1][t];
}

// ---------------------------------------------------------------------------
// K4d: e[gb][128+d] = sum_chunk wsum / Z
// ---------------------------------------------------------------------------
__global__ __launch_bounds__(128) void k4d_final(const float* __restrict__ wsum,
                                                 const float* __restrict__ mz,
                                                 float* __restrict__ e) {
  const int t = threadIdx.x;
  const int gb = blockIdx.x;
  float s = 0.f;
#pragma unroll
  for (int c = 0; c < 16; ++c) s += wsum[(gb * 16 + c) * 128 + t];
  e[gb * 256 + 128 + t] = s / mz[gb * 2 + 1];
}

// ---------------------------------------------------------------------------
// K5: LED head per batch
// ---------------------------------------------------------------------------
__global__ __launch_bounds__(256) void k5_led(const float* __restrict__ e,
                                              const float* __restrict__ convW,
                                              const float* __restrict__ convb,
                                              const float* __restrict__ ledW1,
                                              const float* __restrict__ ledb1,
                                              const float* __restrict__ ledW2,
                                              const float* __restrict__ ledb2,
                                              float* __restrict__ out) {
  __shared__ float eaL[256], ebL[256], uL[512], xL[128], lgL[2];
  const int t = threadIdx.x;
  const int wave = t >> 6, lane = t & 63;
  const int bt = blockIdx.x;
  if (t < 64) {
    *(float4*)&eaL[t * 4] = *(const float4*)&e[bt * 256 + t * 4];
    *(float4*)&ebL[t * 4] = *(const float4*)&e[(4 + bt) * 256 + t * 4];
  }
  __syncthreads();
  uL[256 + t] = eaL[t] - ebL[t];
  const float4 ea4 = *(const float4*)&eaL[lane * 4];
  const float4 eb4 = *(const float4*)&ebL[lane * 4];
  for (int p = 0; p < 32; ++p) {
    const int o0 = p * 8 + wave * 2;
    const float4 w0 = *(const float4*)&convW[o0 * 256 + lane * 4];
    const float4 w1 = *(const float4*)&convW[(o0 + 1) * 256 + lane * 4];
    float sa0 = dot4(w0, ea4), sb0 = dot4(w0, eb4);
    float sa1 = dot4(w1, ea4), sb1 = dot4(w1, eb4);
#pragma unroll
    for (int s = 1; s < 64; s <<= 1) {
      sa0 += __shfl_xor(sa0, s); sb0 += __shfl_xor(sb0, s);
      sa1 += __shfl_xor(sa1, s); sb1 += __shfl_xor(sb1, s);
    }
    if (lane == 0) {
      const float c0 = convb[o0], c1 = convb[o0 + 1];
      uL[o0] = fmaxf(sa0 + c0, sb0 + c0);
      uL[o0 + 1] = fmaxf(sa1 + c1, sb1 + c1);
    }
  }
  __syncthreads();
  for (int p = 0; p < 16; ++p) {
    const int o0 = p * 8 + wave * 2;
    const float* w0 = &ledW1[o0 * 512 + lane * 8];
    const float* w1 = &ledW1[(o0 + 1) * 512 + lane * 8];
    const float4 u0 = *(const float4*)&uL[lane * 8];
    const float4 u1 = *(const float4*)&uL[lane * 8 + 4];
    float s0 = dot4(*(const float4*)&w0[0], u0) + dot4(*(const float4*)&w0[4], u1);
    float s1v = dot4(*(const float4*)&w1[0], u0) + dot4(*(const float4*)&w1[4], u1);
#pragma unroll
    for (int s = 1; s < 64; s <<= 1) { s0 += __shfl_xor(s0, s); s1v += __shfl_xor(s1v, s); }
    if (lane == 0) {
      xL[o0] = fmaxf(s0 + ledb1[o0], 0.f);
      xL[o0 + 1] = fmaxf(s1v + ledb1[o0 + 1], 0.f);
    }
  }
  __syncthreads();
  if (wave < 2) {
    const float2 w = *(const float2*)&ledW2[wave * 128 + lane * 2];
    const float2 xv = *(const float2*)&xL[lane * 2];
    float s0 = w.x * xv.x + w.y * xv.y;
#pragma unroll
    for (int s = 1; s < 64; s <<= 1) s0 += __shfl_xor(s0, s);
    if (lane == 0) lgL[wave] = s0 + ledb2[wave];
  }
  __syncthreads();
  if (t == 0) {
    const float l0 = lgL[0], l1 = lgL[1];
    const float m = fmaxf(l0, l1);
    const float za = __expf(l0 - m) + __expf(l1 - m);
    const float lz = __logf(za);
    out[bt * 2 + 0] = l0 - m - lz;
    out[bt * 2 + 1] = l1 - m - lz;
  }
}

// ---------------------------------------------------------------------------
extern "C" void kernel_launch(void* const* d_in, const int* in_sizes, int n_in,
                              void* d_out, int out_size, void* d_ws, size_t ws_size,
                              hipStream_t stream) {
  (void)in_sizes; (void)n_in; (void)out_size; (void)ws_size;
  const float* a     = (const float*)d_in[0];
  const float* bioA  = (const float*)d_in[1];
  const int*   A     = (const int*)d_in[2];
  const float* b     = (const float*)d_in[3];
  const float* bioB  = (const float*)d_in[4];
  const int*   B     = (const int*)d_in[5];
  const float* initW = (const float*)d_in[6];
  const float* initb = (const float*)d_in[7];
  const float* projW = (const float*)d_in[8];
  const float* attw  = (const float*)d_in[9];
  const float* attb  = (const float*)d_in[10];
  const float* ggeW1 = (const float*)d_in[11];
  const float* ggeb1 = (const float*)d_in[12];
  const float* ggeW2 = (const float*)d_in[13];
  const float* ggeb2 = (const float*)d_in[14];
  const float* convW = (const float*)d_in[15];
  const float* convb = (const float*)d_in[16];
  const float* ledW1 = (const float*)d_in[17];
  const float* ledb1 = (const float*)d_in[18];
  const float* ledW2 = (const float*)d_in[19];
  const float* ledb2 = (const float*)d_in[20];

  float* ws = (float*)d_ws;
  float*          x    = ws;                              // 2,097,152 f32
  unsigned short* xhT  = (unsigned short*)(ws + 2097152); // 4,194,304 bf16
  float*          s1   = ws + 3145728;                    // 65,536
  float*          s2   = ws + 3211264;                    // 65,536
  float*          G    = ws + 3276800;                    // 2,097,152
  float*          lg   = ws + 5373952;                    // 16,384
  float*          wsum = ws + 5390336;                    // 16,384
  float*          mz   = ws + 5406720;                    // 16
  float*          hv   = ws + 5406736;                    // 1,024
  float*          e    = ws + 5407760;                    // 2,048
  float* out = (float*)d_out;

  k1_init<<<512, 256, 0, stream>>>(bioA, bioB, initW, initb, x);
  k2_proj<<<512, 256, 0, stream>>>(x, projW, attw, xhT, s1, s2);
  k3_attn<<<512, 512, 0, stream>>>(xhT, s1, s2, A, B, attb, x, G);
  k4h_gge<<<8, 256, 0, stream>>>(a, b, ggeW1, ggeb1, ggeW2, ggeb2, hv, e);
  k4a_logits<<<128, 256, 0, stream>>>(G, hv, lg);
  k4b_reduce<<<8, 256, 0, stream>>>(lg, mz);
  k4c_wsum<<<128, 256, 0, stream>>>(G, lg, mz, wsum);
  k4d_final<<<8, 128, 0, stream>>>(wsum, mz, e);
  k5_led<<<4, 256, 0, stream>>>(e, convW, convb, ledW1, ledb1, ledW2, ledb2, out);
}

// Round 4
// 197.208 us; speedup vs baseline: 2.7724x; 1.0143x over previous
//
#include <hip/hip_runtime.h>
#include <hip/hip_bf16.h>
#include <math.h>

#define NN 2048
#define NEG 0.2f
#define LOG2E 1.44269504f

typedef short bf16x8 __attribute__((ext_vector_type(8)));
typedef float f32x16 __attribute__((ext_vector_type(16)));

__device__ __forceinline__ float dot4(float4 a, float4 b) {
  return a.x * b.x + a.y * b.y + a.z * b.z + a.w * b.w;
}

__device__ __forceinline__ unsigned short bfbits(float f) {
  union { __hip_bfloat16 b; unsigned short u; } c;
  c.b = __float2bfloat16(f);
  return c.u;
}

// ---------------------------------------------------------------------------
// K1: x = bio @ initW^T + initb      rows = [g][b][n] (16384), K=256, out 128
// ---------------------------------------------------------------------------
__global__ __launch_bounds__(256) void k1_init(const float* __restrict__ bioA,
                                               const float* __restrict__ bioB,
                                               const float* __restrict__ W,
                                               const float* __restrict__ bias,
                                               float* __restrict__ xout) {
  __shared__ float As[32][36];
  __shared__ float Ws[32][132];
  const int t = threadIdx.x;
  const int m0 = blockIdx.x * 32;
  const float* A = (m0 < 8192) ? bioA : bioB;
  const int arow0 = (m0 < 8192) ? m0 : (m0 - 8192);
  const int og = t & 31, ig = t >> 5;
  float acc[4][4] = {};
  for (int kt = 0; kt < 256; kt += 32) {
    __syncthreads();
    {
      const int r = t >> 3, kq = t & 7;
      const float4 v = *(const float4*)&A[(arow0 + r) * 256 + kt + kq * 4];
      As[kq * 4 + 0][r] = v.x; As[kq * 4 + 1][r] = v.y;
      As[kq * 4 + 2][r] = v.z; As[kq * 4 + 3][r] = v.w;
    }
#pragma unroll
    for (int u = 0; u < 4; ++u) {
      const int f = u * 256 + t;
      const int o = f >> 3, kq = f & 7;
      const float4 v = *(const float4*)&W[o * 256 + kt + kq * 4];
      Ws[kq * 4 + 0][o] = v.x; Ws[kq * 4 + 1][o] = v.y;
      Ws[kq * 4 + 2][o] = v.z; Ws[kq * 4 + 3][o] = v.w;
    }
    __syncthreads();
#pragma unroll
    for (int kk = 0; kk < 32; ++kk) {
      const float4 a4 = *(const float4*)&As[kk][ig * 4];
      const float4 w4 = *(const float4*)&Ws[kk][og * 4];
      const float av[4] = {a4.x, a4.y, a4.z, a4.w};
      const float wv[4] = {w4.x, w4.y, w4.z, w4.w};
#pragma unroll
      for (int ii = 0; ii < 4; ++ii)
#pragma unroll
        for (int jj = 0; jj < 4; ++jj) acc[ii][jj] += av[ii] * wv[jj];
    }
  }
  const float4 b4 = *(const float4*)&bias[og * 4];
#pragma unroll
  for (int ii = 0; ii < 4; ++ii) {
    const int row = m0 + ig * 4 + ii;
    float4 o4;
    o4.x = acc[ii][0] + b4.x; o4.y = acc[ii][1] + b4.y;
    o4.z = acc[ii][2] + b4.z; o4.w = acc[ii][3] + b4.w;
    *(float4*)&xout[row * 128 + og * 4] = o4;
  }
}

// ---------------------------------------------------------------------------
// K2: y = x @ projW^T ; write xhT bf16 [gb][h][k=32][n=2048] ; s1,s2 f32
// ---------------------------------------------------------------------------
__global__ __launch_bounds__(256) void k2_proj(const float* __restrict__ x,
                                               const float* __restrict__ W,
                                               const float* __restrict__ attw,
                                               unsigned short* __restrict__ xhT,
                                               float* __restrict__ s1,
                                               float* __restrict__ s2) {
  __shared__ float As[32][36];
  __shared__ float Ws[32][132];
  const int t = threadIdx.x;
  const int m0 = blockIdx.x * 32;
  const int og = t & 31, ig = t >> 5;
  float acc[4][4] = {};
  for (int kt = 0; kt < 128; kt += 32) {
    __syncthreads();
    {
      const int r = t >> 3, kq = t & 7;
      const float4 v = *(const float4*)&x[(m0 + r) * 128 + kt + kq * 4];
      As[kq * 4 + 0][r] = v.x; As[kq * 4 + 1][r] = v.y;
      As[kq * 4 + 2][r] = v.z; As[kq * 4 + 3][r] = v.w;
    }
#pragma unroll
    for (int u = 0; u < 4; ++u) {
      const int f = u * 256 + t;
      const int o = f >> 3, kq = f & 7;
      const float4 v = *(const float4*)&W[o * 128 + kt + kq * 4];
      Ws[kq * 4 + 0][o] = v.x; Ws[kq * 4 + 1][o] = v.y;
      Ws[kq * 4 + 2][o] = v.z; Ws[kq * 4 + 3][o] = v.w;
    }
    __syncthreads();
#pragma unroll
    for (int kk = 0; kk < 32; ++kk) {
      const float4 a4 = *(const float4*)&As[kk][ig * 4];
      const float4 w4 = *(const float4*)&Ws[kk][og * 4];
      const float av[4] = {a4.x, a4.y, a4.z, a4.w};
      const float wv[4] = {w4.x, w4.y, w4.z, w4.w};
#pragma unroll
      for (int ii = 0; ii < 4; ++ii)
#pragma unroll
        for (int jj = 0; jj < 4; ++jj) acc[ii][jj] += av[ii] * wv[jj];
    }
  }
  const int h = og >> 3;
  const int k4i = (og & 7) * 4;
  const int g = m0 >> 13;
  const int bb = (m0 >> 11) & 3;
  const int gb = g * 4 + bb;
  const int n0 = (m0 & 2047) + ig * 4;
  const float4 w1 = *(const float4*)&attw[h * 64 + k4i];
  const float4 w2 = *(const float4*)&attw[h * 64 + 32 + k4i];
  float p1[4], p2[4];
#pragma unroll
  for (int ii = 0; ii < 4; ++ii) {
    float4 v;
    v.x = acc[ii][0]; v.y = acc[ii][1]; v.z = acc[ii][2]; v.w = acc[ii][3];
    p1[ii] = dot4(v, w1);
    p2[ii] = dot4(v, w2);
  }
#pragma unroll
  for (int jj = 0; jj < 4; ++jj) {
    const int kin = k4i + jj;
    ushort4 u;
    u.x = bfbits(acc[0][jj]); u.y = bfbits(acc[1][jj]);
    u.z = bfbits(acc[2][jj]); u.w = bfbits(acc[3][jj]);
    *(ushort4*)&xhT[((gb * 4 + h) * 32 + kin) * NN + n0] = u;
  }
#pragma unroll
  for (int s = 1; s < 8; s <<= 1) {
#pragma unroll
    for (int ii = 0; ii < 4; ++ii) {
      p1[ii] += __shfl_xor(p1[ii], s);
      p2[ii] += __shfl_xor(p2[ii], s);
    }
  }
  if ((og & 7) == 0) {
#pragma unroll
    for (int ii = 0; ii < 4; ++ii) {
      s1[(gb * 4 + h) * NN + n0 + ii] = p1[ii];
      s2[(gb * 4 + h) * NN + n0 + ii] = p2[ii];
    }
  }
}

// ---------------------------------------------------------------------------
// K3: GAT attention via MFMA. block = (g,b, 32-row i-tile), 512 threads.
// wave = (jhalf, head). 4-deep B-frag prefetch ring hides L2 latency.
// ---------------------------------------------------------------------------
__global__ __launch_bounds__(512) void k3_attn(const unsigned short* __restrict__ xhT,
                                               const float* __restrict__ s1w,
                                               const float* __restrict__ s2w,
                                               const int* __restrict__ adjA,
                                               const int* __restrict__ adjB,
                                               const float* __restrict__ attb,
                                               const float* __restrict__ x,
                                               float* __restrict__ G) {
  __shared__ unsigned int adjL[32][66];  // stride 66 words: <=2-way alias (free)
  __shared__ float s2L[4][2048];         // pre-scaled by LOG2E
  __shared__ float accR[4][16][65];      // jhalf=1 partial acc, +1 pad
  __shared__ float denR[4][2][32];
  const int t = threadIdx.x;
  const int wave = t >> 6, lane = t & 63;
  const int blk = blockIdx.x;
  const int g = blk >> 8, b = (blk >> 6) & 3;
  const int i0 = (blk & 63) * 32;
  const int gb = g * 4 + b;
  const int* adj = (g ? adjB : adjA) + (b * NN + i0) * NN;
  // ---- stage s2 * LOG2E for all 4 heads (8192 floats, 512 threads) ----
  {
    const float* s2g = s2w + gb * 4 * NN;
    float* s2f = &s2L[0][0];
#pragma unroll
    for (int u = 0; u < 4; ++u) {
      const int idx = u * 2048 + t * 4;
      float4 v = *(const float4*)&s2g[idx];
      v.x *= LOG2E; v.y *= LOG2E; v.z *= LOG2E; v.w *= LOG2E;
      *(float4*)&s2f[idx] = v;
    }
  }
  // ---- ballot-pack 32 adjacency rows into LDS bitmask (4 rows/wave) ----
#pragma unroll
  for (int r4 = 0; r4 < 4; ++r4) {
    const int r = wave * 4 + r4;
    const int* arow = adj + r * NN;
#pragma unroll 4
    for (int w = 0; w < 32; ++w) {
      const int av = arow[w * 64 + lane];
      const unsigned long long m = __ballot(av > 0);
      if (lane < 2) adjL[r][2 * w + lane] = (unsigned int)(m >> (32 * lane));
    }
  }
  __syncthreads();

  const int h = wave & 3;
  const int jhalf = wave >> 2;
  const int jlo = jhalf * 1024;
  const int i = lane & 31;       // A row / D col index
  const int jslot = lane >> 5;
  const float sc1v = (s1w[(gb * 4 + h) * NN + i0 + i] + attb[h]) * LOG2E;
  // half-iterations linearize: frag m (0..63) at bbase[16*m]
  const unsigned short* bbase = xhT + ((gb * 4 + h) * 32 + i) * NN + jlo + jslot * 8;
  f32x16 acc = {0.f, 0.f, 0.f, 0.f, 0.f, 0.f, 0.f, 0.f,
                0.f, 0.f, 0.f, 0.f, 0.f, 0.f, 0.f, 0.f};
  float den4[4] = {0.f, 0.f, 0.f, 0.f};
  bf16x8 buf[4];
#pragma unroll
  for (int q = 0; q < 4; ++q) buf[q] = *(const bf16x8*)&bbase[16 * q];
  for (int mb = 0; mb < 64; mb += 4) {
#pragma unroll
    for (int q = 0; q < 4; ++q) {
      const int m = mb + q;
      // prefetch 4 frags ahead (tail overreads <=112B into ws: safe)
      const bf16x8 bnext = *(const bf16x8*)&bbase[16 * (m + 4)];
      const int j0 = jlo + 16 * m + jslot * 8;
      const unsigned int wbits = adjL[i][(jlo + 16 * m) >> 5];
      const unsigned int bits8 = wbits >> ((m & 1) * 16 + jslot * 8);
      const float4 s2a = *(const float4*)&s2L[h][j0];
      const float4 s2b = *(const float4*)&s2L[h][j0 + 4];
      const float sv[8] = {s2a.x, s2a.y, s2a.z, s2a.w, s2b.x, s2b.y, s2b.z, s2b.w};
      union { bf16x8 v; unsigned short u[8]; } af;
      float dsum = 0.f;
#pragma unroll
      for (int e = 0; e < 8; ++e) {
        float s = sc1v + sv[e];
        s = fmaxf(s, NEG * s);                     // leaky (scale-invariant)
        float pe = __builtin_amdgcn_exp2f(s);
        pe = ((bits8 >> e) & 1u) ? pe : 0.f;
        af.u[e] = bfbits(pe);
        dsum += pe;
      }
      den4[q] += dsum;
      acc = __builtin_amdgcn_mfma_f32_32x32x16_bf16(af.v, buf[q], acc, 0, 0, 0);
      buf[q] = bnext;
    }
  }
  float den = (den4[0] + den4[1]) + (den4[2] + den4[3]);
  den += __shfl_xor(den, 32);
  if (lane < 32) denR[h][jhalf][lane] = den;
  if (jhalf == 1) {
#pragma unroll
    for (int r = 0; r < 16; ++r) accR[h][r][lane] = acc[r];
  }
  __syncthreads();
  if (jhalf == 0) {
    // D layout (32x32): col = lane&31, row = (reg&3) + 8*(reg>>2) + 4*(lane>>5)
#pragma unroll
    for (int r = 0; r < 16; ++r) {
      const int row = (r & 3) + 8 * (r >> 2) + 4 * jslot;
      const float dinv = 1.f / (denR[h][0][row] + denR[h][1][row]);
      const int off = (gb * NN + i0 + row) * 128 + h * 32 + i;
      const float av = acc[r] + accR[h][r][lane];
      G[off] = fmaxf(av * dinv, 0.f) + x[off];
    }
  }
}

// ---------------------------------------------------------------------------
// K4h: per (g,b): hv = GGE(in); e[gb][0:128] = hv; hvbuf[gb] = hv
// ---------------------------------------------------------------------------
__global__ __launch_bounds__(256) void k4h_gge(const float* __restrict__ a_in,
                                               const float* __restrict__ b_in,
                                               const float* __restrict__ ggeW1,
                                               const float* __restrict__ ggeb1,
                                               const float* __restrict__ ggeW2,
                                               const float* __restrict__ ggeb2,
                                               float* __restrict__ hvbuf,
                                               float* __restrict__ e) {
  __shared__ float inL[512];
  __shared__ float h1L[128];
  const int t = threadIdx.x;
  const int wave = t >> 6, lane = t & 63;
  const int g = blockIdx.x >> 2, b = blockIdx.x & 3;
  const int gb2 = g * 4 + b;
  const float* inp = (g ? b_in : a_in) + b * 512;
  if (t < 128) *(float4*)&inL[t * 4] = *(const float4*)&inp[t * 4];
  __syncthreads();
  for (int p = 0; p < 16; ++p) {
    const int o0 = p * 8 + wave * 2;
    const float* w0 = &ggeW1[o0 * 512 + lane * 8];
    const float* w1 = &ggeW1[(o0 + 1) * 512 + lane * 8];
    const float4 i0v = *(const float4*)&inL[lane * 8];
    const float4 i1v = *(const float4*)&inL[lane * 8 + 4];
    float s0 = dot4(*(const float4*)&w0[0], i0v) + dot4(*(const float4*)&w0[4], i1v);
    float s1v = dot4(*(const float4*)&w1[0], i0v) + dot4(*(const float4*)&w1[4], i1v);
#pragma unroll
    for (int s = 1; s < 64; s <<= 1) { s0 += __shfl_xor(s0, s); s1v += __shfl_xor(s1v, s); }
    if (lane == 0) {
      h1L[o0] = fmaxf(s0 + ggeb1[o0], 0.f);
      h1L[o0 + 1] = fmaxf(s1v + ggeb1[o0 + 1], 0.f);
    }
  }
  __syncthreads();
  for (int p = 0; p < 16; ++p) {
    const int o0 = p * 8 + wave * 2;
    const float2 w0 = *(const float2*)&ggeW2[o0 * 128 + lane * 2];
    const float2 w1 = *(const float2*)&ggeW2[(o0 + 1) * 128 + lane * 2];
    const float2 hvv = *(const float2*)&h1L[lane * 2];
    float s0 = w0.x * hvv.x + w0.y * hvv.y;
    float s1v = w1.x * hvv.x + w1.y * hvv.y;
#pragma unroll
    for (int s = 1; s < 64; s <<= 1) { s0 += __shfl_xor(s0, s); s1v += __shfl_xor(s1v, s); }
    if (lane == 0) {
      const float v0 = fmaxf(s0 + ggeb2[o0], 0.f);
      const float v1 = fmaxf(s1v + ggeb2[o0 + 1], 0.f);
      hvbuf[gb2 * 128 + o0] = v0;
      hvbuf[gb2 * 128 + o0 + 1] = v1;
      e[gb2 * 256 + o0] = v0;
      e[gb2 * 256 + o0 + 1] = v1;
    }
  }
}

// ---------------------------------------------------------------------------
// K4a: GAGA logits lg[gb][n] = G[n,:].hv   grid = gb*16 chunks
// ---------------------------------------------------------------------------
__global__ __launch_bounds__(256) void k4a_logits(const float* __restrict__ G,
                                                  const float* __restrict__ hv,
                                                  float* __restrict__ lg) {
  const int t = threadIdx.x;
  const int wave = t >> 6, lane = t & 63;
  const int gb = blockIdx.x >> 4, chunk = blockIdx.x & 15;
  const float2 hvv = *(const float2*)&hv[gb * 128 + lane * 2];
  const float* Gb = G + gb * NN * 128;
  const int nbase = chunk * 128 + wave * 32;
  for (int q = 0; q < 32; ++q) {
    const int n = nbase + q;
    const float2 gv = *(const float2*)&Gb[n * 128 + lane * 2];
    float part = gv.x * hvv.x + gv.y * hvv.y;
#pragma unroll
    for (int s = 1; s < 64; s <<= 1) part += __shfl_xor(part, s);
    if (lane == 0) lg[gb * NN + n] = part;
  }
}

// ---------------------------------------------------------------------------
// K4b: per gb: max and Z over 2048 logits
// ---------------------------------------------------------------------------
__global__ __launch_bounds__(256) void k4b_reduce(const float* __restrict__ lg,
                                                  float* __restrict__ mz) {
  __shared__ float red[256];
  const int t = threadIdx.x;
  const int gb = blockIdx.x;
  const float* l = lg + gb * NN;
  float m = -1e30f;
  for (int n = t; n < NN; n += 256) m = fmaxf(m, l[n]);
  red[t] = m; __syncthreads();
#pragma unroll
  for (int s = 128; s > 0; s >>= 1) {
    if (t < s) red[t] = fmaxf(red[t], red[t + s]);
    __syncthreads();
  }
  const float mx = red[0]; __syncthreads();
  float z = 0.f;
  for (int n = t; n < NN; n += 256) z += __expf(l[n] - mx);
  red[t] = z; __syncthreads();
#pragma unroll
  for (int s = 128; s > 0; s >>= 1) {
    if (t < s) red[t] += red[t + s];
    __syncthreads();
  }
  if (t == 0) { mz[gb * 2] = mx; mz[gb * 2 + 1] = red[0]; }
}

// ---------------------------------------------------------------------------
// K4c: partial weighted sums wsum[gb][chunk][128] over 128-n chunks
// ---------------------------------------------------------------------------
__global__ __launch_bounds__(256) void k4c_wsum(const float* __restrict__ G,
                                                const float* __restrict__ lg,
                                                const float* __restrict__ mz,
                                                float* __restrict__ wsum) {
  __shared__ float pL[128];
  __shared__ float red[2][128];
  const int t = threadIdx.x;
  const int gb = blockIdx.x >> 4, chunk = blockIdx.x & 15;
  const float mx = mz[gb * 2];
  if (t < 128) pL[t] = __expf(lg[gb * NN + chunk * 128 + t] - mx);
  __syncthreads();
  const int d = t & 127, half = t >> 7;
  const float* Gb = G + (gb * NN + chunk * 128 + half * 64) * 128;
  float acc = 0.f;
  for (int q = 0; q < 64; ++q) acc += pL[half * 64 + q] * Gb[q * 128 + d];
  red[half][d] = acc;
  __syncthreads();
  if (t < 128) wsum[(gb * 16 + chunk) * 128 + t] = red[0][t] + red[1][t];
}

// ---------------------------------------------------------------------------
// K4d: e[gb][128+d] = sum_chunk wsum / Z
// ---------------------------------------------------------------------------
__global__ __launch_bounds__(128) void k4d_final(const float* __restrict__ wsum,
                                                 const float* __restrict__ mz,
                                                 float* __restrict__ e) {
  const int t = threadIdx.x;
  const int gb = blockIdx.x;
  float s = 0.f;
#pragma unroll
  for (int c = 0; c < 16; ++c) s += wsum[(gb * 16 + c) * 128 + t];
  e[gb * 256 + 128 + t] = s / mz[gb * 2 + 1];
}

// ---------------------------------------------------------------------------
// K5: LED head per batch
// ---------------------------------------------------------------------------
__global__ __launch_bounds__(256) void k5_led(const float* __restrict__ e,
                                              const float* __restrict__ convW,
                                              const float* __restrict__ convb,
                                              const float* __restrict__ ledW1,
                                              const float* __restrict__ ledb1,
                                              const float* __restrict__ ledW2,
                                              const float* __restrict__ ledb2,
                                              float* __restrict__ out) {
  __shared__ float eaL[256], ebL[256], uL[512], xL[128], lgL[2];
  const int t = threadIdx.x;
  const int wave = t >> 6, lane = t & 63;
  const int bt = blockIdx.x;
  if (t < 64) {
    *(float4*)&eaL[t * 4] = *(const float4*)&e[bt * 256 + t * 4];
    *(float4*)&ebL[t * 4] = *(const float4*)&e[(4 + bt) * 256 + t * 4];
  }
  __syncthreads();
  uL[256 + t] = eaL[t] - ebL[t];
  const float4 ea4 = *(const float4*)&eaL[lane * 4];
  const float4 eb4 = *(const float4*)&ebL[lane * 4];
  for (int p = 0; p < 32; ++p) {
    const int o0 = p * 8 + wave * 2;
    const float4 w0 = *(const float4*)&convW[o0 * 256 + lane * 4];
    const float4 w1 = *(const float4*)&convW[(o0 + 1) * 256 + lane * 4];
    float sa0 = dot4(w0, ea4), sb0 = dot4(w0, eb4);
    float sa1 = dot4(w1, ea4), sb1 = dot4(w1, eb4);
#pragma unroll
    for (int s = 1; s < 64; s <<= 1) {
      sa0 += __shfl_xor(sa0, s); sb0 += __shfl_xor(sb0, s);
      sa1 += __shfl_xor(sa1, s); sb1 += __shfl_xor(sb1, s);
    }
    if (lane == 0) {
      const float c0 = convb[o0], c1 = convb[o0 + 1];
      uL[o0] = fmaxf(sa0 + c0, sb0 + c0);
      uL[o0 + 1] = fmaxf(sa1 + c1, sb1 + c1);
    }
  }
  __syncthreads();
  for (int p = 0; p < 16; ++p) {
    const int o0 = p * 8 + wave * 2;
    const float* w0 = &ledW1[o0 * 512 + lane * 8];
    const float* w1 = &ledW1[(o0 + 1) * 512 + lane * 8];
    const float4 u0 = *(const float4*)&uL[lane * 8];
    const float4 u1 = *(const float4*)&uL[lane * 8 + 4];
    float s0 = dot4(*(const float4*)&w0[0], u0) + dot4(*(const float4*)&w0[4], u1);
    float s1v = dot4(*(const float4*)&w1[0], u0) + dot4(*(const float4*)&w1[4], u1);
#pragma unroll
    for (int s = 1; s < 64; s <<= 1) { s0 += __shfl_xor(s0, s); s1v += __shfl_xor(s1v, s); }
    if (lane == 0) {
      xL[o0] = fmaxf(s0 + ledb1[o0], 0.f);
      xL[o0 + 1] = fmaxf(s1v + ledb1[o0 + 1], 0.f);
    }
  }
  __syncthreads();
  if (wave < 2) {
    const float2 w = *(const float2*)&ledW2[wave * 128 + lane * 2];
    const float2 xv = *(const float2*)&xL[lane * 2];
    float s0 = w.x * xv.x + w.y * xv.y;
#pragma unroll
    for (int s = 1; s < 64; s <<= 1) s0 += __shfl_xor(s0, s);
    if (lane == 0) lgL[wave] = s0 + ledb2[wave];
  }
  __syncthreads();
  if (t == 0) {
    const float l0 = lgL[0], l1 = lgL[1];
    const float m = fmaxf(l0, l1);
    const float za = __expf(l0 - m) + __expf(l1 - m);
    const float lz = __logf(za);
    out[bt * 2 + 0] = l0 - m - lz;
    out[bt * 2 + 1] = l1 - m - lz;
  }
}

// ---------------------------------------------------------------------------
extern "C" void kernel_launch(void* const* d_in, const int* in_sizes, int n_in,
                              void* d_out, int out_size, void* d_ws, size_t ws_size,
                              hipStream_t stream) {
  (void)in_sizes; (void)n_in; (void)out_size; (void)ws_size;
  const float* a     = (const float*)d_in[0];
  const float* bioA  = (const float*)d_in[1];
  const int*   A     = (const int*)d_in[2];
  const float* b     = (const float*)d_in[3];
  const float* bioB  = (const float*)d_in[4];
  const int*   B     = (const int*)d_in[5];
  const float* initW = (const float*)d_in[6];
  const float* initb = (const float*)d_in[7];
  const float* projW = (const float*)d_in[8];
  const float* attw  = (const float*)d_in[9];
  const float* attb  = (const float*)d_in[10];
  const float* ggeW1 = (const float*)d_in[11];
  const float* ggeb1 = (const float*)d_in[12];
  const float* ggeW2 = (const float*)d_in[13];
  const float* ggeb2 = (const float*)d_in[14];
  const float* convW = (const float*)d_in[15];
  const float* convb = (const float*)d_in[16];
  const float* ledW1 = (const float*)d_in[17];
  const float* ledb1 = (const float*)d_in[18];
  const float* ledW2 = (const float*)d_in[19];
  const float* ledb2 = (const float*)d_in[20];

  float* ws = (float*)d_ws;
  float*          x    = ws;                              // 2,097,152 f32
  unsigned short* xhT  = (unsigned short*)(ws + 2097152); // 4,194,304 bf16
  float*          s1   = ws + 3145728;                    // 65,536
  float*          s2   = ws + 3211264;                    // 65,536
  float*          G    = ws + 3276800;                    // 2,097,152
  float*          lg   = ws + 5373952;                    // 16,384
  float*          wsum = ws + 5390336;                    // 16,384
  float*          mz   = ws + 5406720;                    // 16
  float*          hv   = ws + 5406736;                    // 1,024
  float*          e    = ws + 5407760;                    // 2,048
  float* out = (float*)d_out;

  k1_init<<<512, 256, 0, stream>>>(bioA, bioB, initW, initb, x);
  k2_proj<<<512, 256, 0, stream>>>(x, projW, attw, xhT, s1, s2);
  k3_attn<<<512, 512, 0, stream>>>(xhT, s1, s2, A, B, attb, x, G);
  k4h_gge<<<8, 256, 0, stream>>>(a, b, ggeW1, ggeb1, ggeW2, ggeb2, hv, e);
  k4a_logits<<<128, 256, 0, stream>>>(G, hv, lg);
  k4b_reduce<<<8, 256, 0, stream>>>(lg, mz);
  k4c_wsum<<<128, 256, 0, stream>>>(G, lg, mz, wsum);
  k4d_final<<<8, 128, 0, stream>>>(wsum, mz, e);
  k5_led<<<4, 256, 0, stream>>>(e, convW, convb, ledW1, ledb1, ledW2, ledb2, out);
}

// Round 6
// 195.661 us; speedup vs baseline: 2.7943x; 1.0079x over previous
//
#include <hip/hip_runtime.h>
#include <hip/hip_bf16.h>
#include <math.h>

#define NN 2048
#define NEG 0.2f
#define LOG2E 1.44269504f

typedef short bf16x8 __attribute__((ext_vector_type(8)));
typedef float f32x16 __attribute__((ext_vector_type(16)));

__device__ __forceinline__ float dot4(float4 a, float4 b) {
  return a.x * b.x + a.y * b.y + a.z * b.z + a.w * b.w;
}

__device__ __forceinline__ unsigned short bfbits(float f) {
  union { __hip_bfloat16 b; unsigned short u; } c;
  c.b = __float2bfloat16(f);
  return c.u;
}

// ---------------------------------------------------------------------------
// K1: x = bio @ initW^T + initb      rows = [g][b][n] (16384), K=256, out 128
// ---------------------------------------------------------------------------
__global__ __launch_bounds__(256) void k1_init(const float* __restrict__ bioA,
                                               const float* __restrict__ bioB,
                                               const float* __restrict__ W,
                                               const float* __restrict__ bias,
                                               float* __restrict__ xout) {
  __shared__ float As[32][36];
  __shared__ float Ws[32][132];
  const int t = threadIdx.x;
  const int m0 = blockIdx.x * 32;
  const float* A = (m0 < 8192) ? bioA : bioB;
  const int arow0 = (m0 < 8192) ? m0 : (m0 - 8192);
  const int og = t & 31, ig = t >> 5;
  float acc[4][4] = {};
  for (int kt = 0; kt < 256; kt += 32) {
    __syncthreads();
    {
      const int r = t >> 3, kq = t & 7;
      const float4 v = *(const float4*)&A[(arow0 + r) * 256 + kt + kq * 4];
      As[kq * 4 + 0][r] = v.x; As[kq * 4 + 1][r] = v.y;
      As[kq * 4 + 2][r] = v.z; As[kq * 4 + 3][r] = v.w;
    }
#pragma unroll
    for (int u = 0; u < 4; ++u) {
      const int f = u * 256 + t;
      const int o = f >> 3, kq = f & 7;
      const float4 v = *(const float4*)&W[o * 256 + kt + kq * 4];
      Ws[kq * 4 + 0][o] = v.x; Ws[kq * 4 + 1][o] = v.y;
      Ws[kq * 4 + 2][o] = v.z; Ws[kq * 4 + 3][o] = v.w;
    }
    __syncthreads();
#pragma unroll
    for (int kk = 0; kk < 32; ++kk) {
      const float4 a4 = *(const float4*)&As[kk][ig * 4];
      const float4 w4 = *(const float4*)&Ws[kk][og * 4];
      const float av[4] = {a4.x, a4.y, a4.z, a4.w};
      const float wv[4] = {w4.x, w4.y, w4.z, w4.w};
#pragma unroll
      for (int ii = 0; ii < 4; ++ii)
#pragma unroll
        for (int jj = 0; jj < 4; ++jj) acc[ii][jj] += av[ii] * wv[jj];
    }
  }
  const float4 b4 = *(const float4*)&bias[og * 4];
#pragma unroll
  for (int ii = 0; ii < 4; ++ii) {
    const int row = m0 + ig * 4 + ii;
    float4 o4;
    o4.x = acc[ii][0] + b4.x; o4.y = acc[ii][1] + b4.y;
    o4.z = acc[ii][2] + b4.z; o4.w = acc[ii][3] + b4.w;
    *(float4*)&xout[row * 128 + og * 4] = o4;
  }
}

// ---------------------------------------------------------------------------
// K2: y = x @ projW^T ; write xhT2 bf16 tile-major [gb][h][m][jslot][k][j8]
// (one MFMA B-frag = contiguous 1KB per wave in k3); s1,s2 f32
// ---------------------------------------------------------------------------
__global__ __launch_bounds__(256) void k2_proj(const float* __restrict__ x,
                                               const float* __restrict__ W,
                                               const float* __restrict__ attw,
                                               unsigned short* __restrict__ xhT2,
                                               float* __restrict__ s1,
                                               float* __restrict__ s2) {
  __shared__ float As[32][36];
  __shared__ float Ws[32][132];
  const int t = threadIdx.x;
  const int m0 = blockIdx.x * 32;
  const int og = t & 31, ig = t >> 5;
  float acc[4][4] = {};
  for (int kt = 0; kt < 128; kt += 32) {
    __syncthreads();
    {
      const int r = t >> 3, kq = t & 7;
      const float4 v = *(const float4*)&x[(m0 + r) * 128 + kt + kq * 4];
      As[kq * 4 + 0][r] = v.x; As[kq * 4 + 1][r] = v.y;
      As[kq * 4 + 2][r] = v.z; As[kq * 4 + 3][r] = v.w;
    }
#pragma unroll
    for (int u = 0; u < 4; ++u) {
      const int f = u * 256 + t;
      const int o = f >> 3, kq = f & 7;
      const float4 v = *(const float4*)&W[o * 128 + kt + kq * 4];
      Ws[kq * 4 + 0][o] = v.x; Ws[kq * 4 + 1][o] = v.y;
      Ws[kq * 4 + 2][o] = v.z; Ws[kq * 4 + 3][o] = v.w;
    }
    __syncthreads();
#pragma unroll
    for (int kk = 0; kk < 32; ++kk) {
      const float4 a4 = *(const float4*)&As[kk][ig * 4];
      const float4 w4 = *(const float4*)&Ws[kk][og * 4];
      const float av[4] = {a4.x, a4.y, a4.z, a4.w};
      const float wv[4] = {w4.x, w4.y, w4.z, w4.w};
#pragma unroll
      for (int ii = 0; ii < 4; ++ii)
#pragma unroll
        for (int jj = 0; jj < 4; ++jj) acc[ii][jj] += av[ii] * wv[jj];
    }
  }
  const int h = og >> 3;
  const int k4i = (og & 7) * 4;
  const int g = m0 >> 13;
  const int bb = (m0 >> 11) & 3;
  const int gb = g * 4 + bb;
  const int n0 = (m0 & 2047) + ig * 4;
  const float4 w1 = *(const float4*)&attw[h * 64 + k4i];
  const float4 w2 = *(const float4*)&attw[h * 64 + 32 + k4i];
  float p1[4], p2[4];
#pragma unroll
  for (int ii = 0; ii < 4; ++ii) {
    float4 v;
    v.x = acc[ii][0]; v.y = acc[ii][1]; v.z = acc[ii][2]; v.w = acc[ii][3];
    p1[ii] = dot4(v, w1);
    p2[ii] = dot4(v, w2);
  }
  // tile-major store: [gb][h][m=n>>4][jslot=(n>>3)&1][k][j8=n&7]
  {
    const int mtile = n0 >> 4, jslot = (n0 >> 3) & 1, j8 = n0 & 7;
    const int base2 = ((((gb * 4 + h) * 128 + mtile) * 2 + jslot) * 32) * 8 + j8;
#pragma unroll
    for (int jj = 0; jj < 4; ++jj) {
      const int kin = k4i + jj;
      ushort4 u;
      u.x = bfbits(acc[0][jj]); u.y = bfbits(acc[1][jj]);
      u.z = bfbits(acc[2][jj]); u.w = bfbits(acc[3][jj]);
      *(ushort4*)&xhT2[base2 + kin * 8] = u;
    }
  }
#pragma unroll
  for (int s = 1; s < 8; s <<= 1) {
#pragma unroll
    for (int ii = 0; ii < 4; ++ii) {
      p1[ii] += __shfl_xor(p1[ii], s);
      p2[ii] += __shfl_xor(p2[ii], s);
    }
  }
  if ((og & 7) == 0) {
#pragma unroll
    for (int ii = 0; ii < 4; ++ii) {
      s1[(gb * 4 + h) * NN + n0 + ii] = p1[ii];
      s2[(gb * 4 + h) * NN + n0 + ii] = p2[ii];
    }
  }
}

// ---------------------------------------------------------------------------
// K3: GAT attention via MFMA. block = (g,b, 32-row i-tile), 512 threads.
// wave = (jhalf, head). B-frags are contiguous 1KB/wave (tile-major xhT2).
// ---------------------------------------------------------------------------
__global__ __launch_bounds__(512) void k3_attn(const unsigned short* __restrict__ xhT2,
                                               const float* __restrict__ s1w,
                                               const float* __restrict__ s2w,
                                               const int* __restrict__ adjA,
                                               const int* __restrict__ adjB,
                                               const float* __restrict__ attb,
                                               const float* __restrict__ x,
                                               float* __restrict__ G) {
  __shared__ unsigned int adjL[32][66];  // stride 66 words: <=2-way alias (free)
  __shared__ float s2L[4][2048];         // pre-scaled by LOG2E
  __shared__ float accR[4][16][65];      // jhalf=1 partial acc, +1 pad
  __shared__ float denR[4][2][32];
  const int t = threadIdx.x;
  const int wave = t >> 6, lane = t & 63;
  const int blk = blockIdx.x;
  const int g = blk >> 8, b = (blk >> 6) & 3;
  const int i0 = (blk & 63) * 32;
  const int gb = g * 4 + b;
  const int* adj = (g ? adjB : adjA) + (b * NN + i0) * NN;
  // ---- stage s2 * LOG2E for all 4 heads (8192 floats, 512 threads) ----
  {
    const float* s2g = s2w + gb * 4 * NN;
    float* s2f = &s2L[0][0];
#pragma unroll
    for (int u = 0; u < 4; ++u) {
      const int idx = u * 2048 + t * 4;
      float4 v = *(const float4*)&s2g[idx];
      v.x *= LOG2E; v.y *= LOG2E; v.z *= LOG2E; v.w *= LOG2E;
      *(float4*)&s2f[idx] = v;
    }
  }
  // ---- ballot-pack 32 adjacency rows into LDS bitmask (4 rows/wave) ----
#pragma unroll
  for (int r4 = 0; r4 < 4; ++r4) {
    const int r = wave * 4 + r4;
    const int* arow = adj + r * NN;
#pragma unroll 4
    for (int w = 0; w < 32; ++w) {
      const int av = arow[w * 64 + lane];
      const unsigned long long m = __ballot(av > 0);
      if (lane < 2) adjL[r][2 * w + lane] = (unsigned int)(m >> (32 * lane));
    }
  }
  __syncthreads();

  const int h = wave & 3;
  const int jhalf = wave >> 2;
  const int jlo = jhalf * 1024;
  const int i = lane & 31;       // A row / D col index
  const int jslot = lane >> 5;
  const float sc1v = (s1w[(gb * 4 + h) * NN + i0 + i] + attb[h]) * LOG2E;
  // B-frag m (local 0..63) at bbase[m*512]; lane offset makes the wave's
  // 64x16B fall in one contiguous 1KB block (fully coalesced).
  // per-(gb,h) stride = 128 tiles * 512 = 65536 elements.
  const unsigned short* bbase = xhT2 + (gb * 4 + h) * 65536 + jhalf * 64 * 512
                                + jslot * 256 + i * 8;
  f32x16 acc = {0.f, 0.f, 0.f, 0.f, 0.f, 0.f, 0.f, 0.f,
                0.f, 0.f, 0.f, 0.f, 0.f, 0.f, 0.f, 0.f};
  float den4[4] = {0.f, 0.f, 0.f, 0.f};
  bf16x8 buf[4];
#pragma unroll
  for (int q = 0; q < 4; ++q) buf[q] = *(const bf16x8*)&bbase[512 * q];
  for (int mb = 0; mb < 64; mb += 4) {
#pragma unroll
    for (int q = 0; q < 4; ++q) {
      const int m = mb + q;
      // prefetch 4 frags ahead (tail overreads ~4KB into ws: safe)
      const bf16x8 bnext = *(const bf16x8*)&bbase[512 * (m + 4)];
      const int j0 = jlo + 16 * m + jslot * 8;
      const unsigned int wbits = adjL[i][(jlo + 16 * m) >> 5];
      const unsigned int bits8 = wbits >> ((m & 1) * 16 + jslot * 8);
      const float4 s2a = *(const float4*)&s2L[h][j0];
      const float4 s2b = *(const float4*)&s2L[h][j0 + 4];
      const float sv[8] = {s2a.x, s2a.y, s2a.z, s2a.w, s2b.x, s2b.y, s2b.z, s2b.w};
      union { bf16x8 v; unsigned short u[8]; } af;
      float dsum = 0.f;
#pragma unroll
      for (int e = 0; e < 8; ++e) {
        float s = sc1v + sv[e];
        s = fmaxf(s, NEG * s);                     // leaky (scale-invariant)
        float pe = __builtin_amdgcn_exp2f(s);
        pe = ((bits8 >> e) & 1u) ? pe : 0.f;
        af.u[e] = bfbits(pe);
        dsum += pe;
      }
      den4[q] += dsum;
      acc = __builtin_amdgcn_mfma_f32_32x32x16_bf16(af.v, buf[q], acc, 0, 0, 0);
      buf[q] = bnext;
    }
  }
  float den = (den4[0] + den4[1]) + (den4[2] + den4[3]);
  den += __shfl_xor(den, 32);
  if (lane < 32) denR[h][jhalf][lane] = den;
  if (jhalf == 1) {
#pragma unroll
    for (int r = 0; r < 16; ++r) accR[h][r][lane] = acc[r];
  }
  __syncthreads();
  if (jhalf == 0) {
    // D layout (32x32): col = lane&31, row = (reg&3) + 8*(reg>>2) + 4*(lane>>5)
#pragma unroll
    for (int r = 0; r < 16; ++r) {
      const int row = (r & 3) + 8 * (r >> 2) + 4 * jslot;
      const float dinv = 1.f / (denR[h][0][row] + denR[h][1][row]);
      const int off = (gb * NN + i0 + row) * 128 + h * 32 + i;
      const float av = acc[r] + accR[h][r][lane];
      G[off] = fmaxf(av * dinv, 0.f) + x[off];
    }
  }
}

// ---------------------------------------------------------------------------
// K4h: per (g,b): hv = GGE(in); e[gb][0:128] = hv; hvbuf[gb] = hv
// ---------------------------------------------------------------------------
__global__ __launch_bounds__(256) void k4h_gge(const float* __restrict__ a_in,
                                               const float* __restrict__ b_in,
                                               const float* __restrict__ ggeW1,
                                               const float* __restrict__ ggeb1,
                                               const float* __restrict__ ggeW2,
                                               const float* __restrict__ ggeb2,
                                               float* __restrict__ hvbuf,
                                               float* __restrict__ e) {
  __shared__ float inL[512];
  __shared__ float h1L[128];
  const int t = threadIdx.x;
  const int wave = t >> 6, lane = t & 63;
  const int g = blockIdx.x >> 2, b = blockIdx.x & 3;
  const int gb2 = g * 4 + b;
  const float* inp = (g ? b_in : a_in) + b * 512;
  if (t < 128) *(float4*)&inL[t * 4] = *(const float4*)&inp[t * 4];
  __syncthreads();
  for (int p = 0; p < 16; ++p) {
    const int o0 = p * 8 + wave * 2;
    const float* w0 = &ggeW1[o0 * 512 + lane * 8];
    const float* w1 = &ggeW1[(o0 + 1) * 512 + lane * 8];
    const float4 i0v = *(const float4*)&inL[lane * 8];
    const float4 i1v = *(const float4*)&inL[lane * 8 + 4];
    float s0 = dot4(*(const float4*)&w0[0], i0v) + dot4(*(const float4*)&w0[4], i1v);
    float s1v = dot4(*(const float4*)&w1[0], i0v) + dot4(*(const float4*)&w1[4], i1v);
#pragma unroll
    for (int s = 1; s < 64; s <<= 1) { s0 += __shfl_xor(s0, s); s1v += __shfl_xor(s1v, s); }
    if (lane == 0) {
      h1L[o0] = fmaxf(s0 + ggeb1[o0], 0.f);
      h1L[o0 + 1] = fmaxf(s1v + ggeb1[o0 + 1], 0.f);
    }
  }
  __syncthreads();
  for (int p = 0; p < 16; ++p) {
    const int o0 = p * 8 + wave * 2;
    const float2 w0 = *(const float2*)&ggeW2[o0 * 128 + lane * 2];
    const float2 w1 = *(const float2*)&ggeW2[(o0 + 1) * 128 + lane * 2];
    const float2 hvv = *(const float2*)&h1L[lane * 2];
    float s0 = w0.x * hvv.x + w0.y * hvv.y;
    float s1v = w1.x * hvv.x + w1.y * hvv.y;
#pragma unroll
    for (int s = 1; s < 64; s <<= 1) { s0 += __shfl_xor(s0, s); s1v += __shfl_xor(s1v, s); }
    if (lane == 0) {
      const float v0 = fmaxf(s0 + ggeb2[o0], 0.f);
      const float v1 = fmaxf(s1v + ggeb2[o0 + 1], 0.f);
      hvbuf[gb2 * 128 + o0] = v0;
      hvbuf[gb2 * 128 + o0 + 1] = v1;
      e[gb2 * 256 + o0] = v0;
      e[gb2 * 256 + o0 + 1] = v1;
    }
  }
}

// ---------------------------------------------------------------------------
// K4a: GAGA logits lg[gb][n] = G[n,:].hv   grid = gb*16 chunks
// ---------------------------------------------------------------------------
__global__ __launch_bounds__(256) void k4a_logits(const float* __restrict__ G,
                                                  const float* __restrict__ hv,
                                                  float* __restrict__ lg) {
  const int t = threadIdx.x;
  const int wave = t >> 6, lane = t & 63;
  const int gb = blockIdx.x >> 4, chunk = blockIdx.x & 15;
  const float2 hvv = *(const float2*)&hv[gb * 128 + lane * 2];
  const float* Gb = G + gb * NN * 128;
  const int nbase = chunk * 128 + wave * 32;
  for (int q = 0; q < 32; ++q) {
    const int n = nbase + q;
    const float2 gv = *(const float2*)&Gb[n * 128 + lane * 2];
    float part = gv.x * hvv.x + gv.y * hvv.y;
#pragma unroll
    for (int s = 1; s < 64; s <<= 1) part += __shfl_xor(part, s);
    if (lane == 0) lg[gb * NN + n] = part;
  }
}

// ---------------------------------------------------------------------------
// K4b: per gb: max and Z over 2048 logits
// ---------------------------------------------------------------------------
__global__ __launch_bounds__(256) void k4b_reduce(const float* __restrict__ lg,
                                                  float* __restrict__ mz) {
  __shared__ float red[256];
  const int t = threadIdx.x;
  const int gb = blockIdx.x;
  const float* l = lg + gb * NN;
  float m = -1e30f;
  for (int n = t; n < NN; n += 256) m = fmaxf(m, l[n]);
  red[t] = m; __syncthreads();
#pragma unroll
  for (int s = 128; s > 0; s >>= 1) {
    if (t < s) red[t] = fmaxf(red[t], red[t + s]);
    __syncthreads();
  }
  const float mx = red[0]; __syncthreads();
  float z = 0.f;
  for (int n = t; n < NN; n += 256) z += __expf(l[n] - mx);
  red[t] = z; __syncthreads();
#pragma unroll
  for (int s = 128; s > 0; s >>= 1) {
    if (t < s) red[t] += red[t + s];
    __syncthreads();
  }
  if (t == 0) { mz[gb * 2] = mx; mz[gb * 2 + 1] = red[0]; }
}

// ---------------------------------------------------------------------------
// K4c: partial weighted sums wsum[gb][chunk][128] over 128-n chunks
// ---------------------------------------------------------------------------
__global__ __launch_bounds__(256) void k4c_wsum(const float* __restrict__ G,
                                                const float* __restrict__ lg,
                                                const float* __restrict__ mz,
                                                float* __restrict__ wsum) {
  __shared__ float pL[128];
  __shared__ float red[2][128];
  const int t = threadIdx.x;
  const int gb = blockIdx.x >> 4, chunk = blockIdx.x & 15;
  const float mx = mz[gb * 2];
  if (t < 128) pL[t] = __expf(lg[gb * NN + chunk * 128 + t] - mx);
  __syncthreads();
  const int d = t & 127, half = t >> 7;
  const float* Gb = G + (gb * NN + chunk * 128 + half * 64) * 128;
  float acc = 0.f;
  for (int q = 0; q < 64; ++q) acc += pL[half * 64 + q] * Gb[q * 128 + d];
  red[half][d] = acc;
  __syncthreads();
  if (t < 128) wsum[(gb * 16 + chunk) * 128 + t] = red[0][t] + red[1][t];
}

// ---------------------------------------------------------------------------
// K4d: e[gb][128+d] = sum_chunk wsum / Z
// ---------------------------------------------------------------------------
__global__ __launch_bounds__(128) void k4d_final(const float* __restrict__ wsum,
                                                 const float* __restrict__ mz,
                                                 float* __restrict__ e) {
  const int t = threadIdx.x;
  const int gb = blockIdx.x;
  float s = 0.f;
#pragma unroll
  for (int c = 0; c < 16; ++c) s += wsum[(gb * 16 + c) * 128 + t];
  e[gb * 256 + 128 + t] = s / mz[gb * 2 + 1];
}

// ---------------------------------------------------------------------------
// K5: LED head per batch
// ---------------------------------------------------------------------------
__global__ __launch_bounds__(256) void k5_led(const float* __restrict__ e,
                                              const float* __restrict__ convW,
                                              const float* __restrict__ convb,
                                              const float* __restrict__ ledW1,
                                              const float* __restrict__ ledb1,
                                              const float* __restrict__ ledW2,
                                              const float* __restrict__ ledb2,
                                              float* __restrict__ out) {
  __shared__ float eaL[256], ebL[256], uL[512], xL[128], lgL[2];
  const int t = threadIdx.x;
  const int wave = t >> 6, lane = t & 63;
  const int bt = blockIdx.x;
  if (t < 64) {
    *(float4*)&eaL[t * 4] = *(const float4*)&e[bt * 256 + t * 4];
    *(float4*)&ebL[t * 4] = *(const float4*)&e[(4 + bt) * 256 + t * 4];
  }
  __syncthreads();
  uL[256 + t] = eaL[t] - ebL[t];
  const float4 ea4 = *(const float4*)&eaL[lane * 4];
  const float4 eb4 = *(const float4*)&ebL[lane * 4];
  for (int p = 0; p < 32; ++p) {
    const int o0 = p * 8 + wave * 2;
    const float4 w0 = *(const float4*)&convW[o0 * 256 + lane * 4];
    const float4 w1 = *(const float4*)&convW[(o0 + 1) * 256 + lane * 4];
    float sa0 = dot4(w0, ea4), sb0 = dot4(w0, eb4);
    float sa1 = dot4(w1, ea4), sb1 = dot4(w1, eb4);
#pragma unroll
    for (int s = 1; s < 64; s <<= 1) {
      sa0 += __shfl_xor(sa0, s); sb0 += __shfl_xor(sb0, s);
      sa1 += __shfl_xor(sa1, s); sb1 += __shfl_xor(sb1, s);
    }
    if (lane == 0) {
      const float c0 = convb[o0], c1 = convb[o0 + 1];
      uL[o0] = fmaxf(sa0 + c0, sb0 + c0);
      uL[o0 + 1] = fmaxf(sa1 + c1, sb1 + c1);
    }
  }
  __syncthreads();
  for (int p = 0; p < 16; ++p) {
    const int o0 = p * 8 + wave * 2;
    const float* w0 = &ledW1[o0 * 512 + lane * 8];
    const float* w1 = &ledW1[(o0 + 1) * 512 + lane * 8];
    const float4 u0 = *(const float4*)&uL[lane * 8];
    const float4 u1 = *(const float4*)&uL[lane * 8 + 4];
    float s0 = dot4(*(const float4*)&w0[0], u0) + dot4(*(const float4*)&w0[4], u1);
    float s1v = dot4(*(const float4*)&w1[0], u0) + dot4(*(const float4*)&w1[4], u1);
#pragma unroll
    for (int s = 1; s < 64; s <<= 1) { s0 += __shfl_xor(s0, s); s1v += __shfl_xor(s1v, s); }
    if (lane == 0) {
      xL[o0] = fmaxf(s0 + ledb1[o0], 0.f);
      xL[o0 + 1] = fmaxf(s1v + ledb1[o0 + 1], 0.f);
    }
  }
  __syncthreads();
  if (wave < 2) {
    const float2 w = *(const float2*)&ledW2[wave * 128 + lane * 2];
    const float2 xv = *(const float2*)&xL[lane * 2];
    float s0 = w.x * xv.x + w.y * xv.y;
#pragma unroll
    for (int s = 1; s < 64; s <<= 1) s0 += __shfl_xor(s0, s);
    if (lane == 0) lgL[wave] = s0 + ledb2[wave];
  }
  __syncthreads();
  if (t == 0) {
    const float l0 = lgL[0], l1 = lgL[1];
    const float m = fmaxf(l0, l1);
    const float za = __expf(l0 - m) + __expf(l1 - m);
    const float lz = __logf(za);
    out[bt * 2 + 0] = l0 - m - lz;
    out[bt * 2 + 1] = l1 - m - lz;
  }
}

// ---------------------------------------------------------------------------
extern "C" void kernel_launch(void* const* d_in, const int* in_sizes, int n_in,
                              void* d_out, int out_size, void* d_ws, size_t ws_size,
                              hipStream_t stream) {
  (void)in_sizes; (void)n_in; (void)out_size; (void)ws_size;
  const float* a     = (const float*)d_in[0];
  const float* bioA  = (const float*)d_in[1];
  const int*   A     = (const int*)d_in[2];
  const float* b     = (const float*)d_in[3];
  const float* bioB  = (const float*)d_in[4];
  const int*   B     = (const int*)d_in[5];
  const float* initW = (const float*)d_in[6];
  const float* initb = (const float*)d_in[7];
  const float* projW = (const float*)d_in[8];
  const float* attw  = (const float*)d_in[9];
  const float* attb  = (const float*)d_in[10];
  const float* ggeW1 = (const float*)d_in[11];
  const float* ggeb1 = (const float*)d_in[12];
  const float* ggeW2 = (const float*)d_in[13];
  const float* ggeb2 = (const float*)d_in[14];
  const float* convW = (const float*)d_in[15];
  const float* convb = (const float*)d_in[16];
  const float* ledW1 = (const float*)d_in[17];
  const float* ledb1 = (const float*)d_in[18];
  const float* ledW2 = (const float*)d_in[19];
  const float* ledb2 = (const float*)d_in[20];

  float* ws = (float*)d_ws;
  float*          x    = ws;                              // 2,097,152 f32
  unsigned short* xhT2 = (unsigned short*)(ws + 2097152); // 4,194,304 bf16 tile-major
  float*          s1   = ws + 3145728;                    // 65,536
  float*          s2   = ws + 3211264;                    // 65,536
  float*          G    = ws + 3276800;                    // 2,097,152
  float*          lg   = ws + 5373952;                    // 16,384
  float*          wsum = ws + 5390336;                    // 16,384
  float*          mz   = ws + 5406720;                    // 16
  float*          hv   = ws + 5406736;                    // 1,024
  float*          e    = ws + 5407760;                    // 2,048
  float* out = (float*)d_out;

  k1_init<<<512, 256, 0, stream>>>(bioA, bioB, initW, initb, x);
  k2_proj<<<512, 256, 0, stream>>>(x, projW, attw, xhT2, s1, s2);
  k3_attn<<<512, 512, 0, stream>>>(xhT2, s1, s2, A, B, attb, x, G);
  k4h_gge<<<8, 256, 0, stream>>>(a, b, ggeW1, ggeb1, ggeW2, ggeb2, hv, e);
  k4a_logits<<<128, 256, 0, stream>>>(G, hv, lg);
  k4b_reduce<<<8, 256, 0, stream>>>(lg, mz);
  k4c_wsum<<<128, 256, 0, stream>>>(G, lg, mz, wsum);
  k4d_final<<<8, 128, 0, stream>>>(wsum, mz, e);
  k5_led<<<4, 256, 0, stream>>>(e, convW, convb, ledW1, ledb1, ledW2, ledb2, out);
}